// Round 3
// baseline (1765.857 us; speedup 1.0000x reference)
//
#include <hip/hip_runtime.h>
#include <math.h>

// Problem constants
#define BB 8
#define SS 2048
#define DM 512
#define DK 64
#define DFF 2048
#define ROWS (BB*SS)          // 16384
#define NTOT (ROWS*DM)        // 8388608
#define LN_EPS 1e-5
#define PAD_IDX 0

typedef __attribute__((ext_vector_type(8))) short short8;
typedef __attribute__((ext_vector_type(4))) short s16x4;
typedef __attribute__((ext_vector_type(4))) float f32x4;

__device__ __forceinline__ short f2b(float f) {        // fp32 -> bf16 (RNE)
    unsigned u = __float_as_uint(f);
    unsigned r = (u + 0x7fffu + ((u >> 16) & 1u)) >> 16;
    return (short)r;
}
__device__ __forceinline__ float b2f(short s) {        // bf16 -> fp32
    return __uint_as_float(((unsigned)(unsigned short)s) << 16);
}

// ---------------------------------------------------------------------------
// Embedding + positional encoding -> trunk T1 (bf16); zero LN stat slots
// ---------------------------------------------------------------------------
__global__ __launch_bounds__(256) void embed_kernel(const int* __restrict__ ids,
                                                    const float* __restrict__ emb,
                                                    short* __restrict__ T1,
                                                    double* __restrict__ red) {
    int idx = blockIdx.x * 256 + threadIdx.x;
    if (idx < 24) red[idx] = 0.0;              // 12 LN slots x (sum,sumsq)
    if (idx >= NTOT) return;
    int d   = idx & (DM - 1);
    int row = idx >> 9;
    int s   = row & (SS - 1);
    int id  = ids[row];
    float e = (id != PAD_IDX) ? emb[(size_t)id * DM + d] : 0.0f;
    float ex  = 2.0f * (float)d / 512.0f;
    float div = powf(10000.0f, ex);
    float arg = (float)s / div;
    float pe  = (d & 1) ? cosf(arg) : sinf(arg);
    T1[idx] = f2b(e + pe);
}

// ---------------------------------------------------------------------------
// Weight packing: WqkvT bf16 [256][512] (rows 192..255 zero) + bqkv fp32[256]
// ---------------------------------------------------------------------------
__global__ __launch_bounds__(256) void packqkvT_kernel(const float* __restrict__ Wq,
                                                       const float* __restrict__ Wk,
                                                       const float* __restrict__ Wv,
                                                       const float* __restrict__ bq,
                                                       const float* __restrict__ bk,
                                                       const float* __restrict__ bv,
                                                       short* __restrict__ WqkvT,
                                                       float* __restrict__ bqkv) {
    int i = blockIdx.x * 256 + threadIdx.x;
    if (i < 256 * 512) {
        int n = i >> 9, k = i & 511;
        float v = (n < 64)  ? Wq[k * 64 + n]
                : (n < 128) ? Wk[k * 64 + (n - 64)]
                : (n < 192) ? Wv[k * 64 + (n - 128)] : 0.0f;
        WqkvT[i] = f2b(v);
    }
    if (i < 256)
        bqkv[i] = (i < 64) ? bq[i] : (i < 128) ? bk[i - 64] : (i < 192) ? bv[i - 128] : 0.0f;
}

// WoST bf16 [512][64]: WoST[e][k] = sum_h Wo[h*64+k][e]
__global__ __launch_bounds__(256) void wosumT_kernel(const float* __restrict__ Wo,
                                                     short* __restrict__ WoST) {
    int i = blockIdx.x * 256 + threadIdx.x;
    if (i >= 512 * 64) return;
    int e = i >> 6, k = i & 63;
    float s = 0.f;
#pragma unroll
    for (int h = 0; h < 8; ++h) s += Wo[(size_t)(h * 64 + k) * 512 + e];
    WoST[i] = f2b(s);
}

// Tiled transpose fp32[R][C] -> bf16[C][R]
__global__ __launch_bounds__(256) void transpose_b16(const float* __restrict__ in,
                                                     short* __restrict__ out,
                                                     int R, int C) {
    __shared__ float tile[32][33];
    int bx = blockIdx.x * 32;
    int by = blockIdx.y * 32;
    int tx = threadIdx.x & 31, ty = threadIdx.x >> 5;
#pragma unroll
    for (int i = 0; i < 32; i += 8)
        tile[ty + i][tx] = in[(size_t)(by + ty + i) * C + bx + tx];
    __syncthreads();
#pragma unroll
    for (int i = 0; i < 32; i += 8)
        out[(size_t)(bx + ty + i) * R + by + tx] = f2b(tile[tx][ty + i]);
}

// Column sums of bf16 weights (for LN folding):
// csq[n<256] = sum_k WqkvT[n][k]; csw1[n<2048] = sum_k W1T[n][k]
__global__ __launch_bounds__(256) void colsum_kernel(const short* __restrict__ WqkvT,
                                                     const short* __restrict__ W1T,
                                                     float* __restrict__ csq,
                                                     float* __restrict__ csw1) {
    int i = blockIdx.x * 256 + threadIdx.x;
    if (i < 256) {
        const short* p = WqkvT + (size_t)i * 512;
        float s = 0.f;
        for (int k = 0; k < 512; ++k) s += b2f(p[k]);
        csq[i] = s;
    } else if (i < 2304) {
        int n = i - 256;
        const short* p = W1T + (size_t)n * 512;
        float s = 0.f;
        for (int k = 0; k < 512; ++k) s += b2f(p[k]);
        csw1[n] = s;
    }
}

// V slice of qkvb [16384][256] -> Vtg bf16 [8][64][2048]
__global__ __launch_bounds__(256) void vtrans_kernel(const short* __restrict__ qkvb,
                                                     short* __restrict__ Vtg) {
    __shared__ short tile[32][40];
    int sx = blockIdx.x * 32;
    int dy = blockIdx.y * 32;
    int b  = blockIdx.z;
    int tx = threadIdx.x & 31, ty = threadIdx.x >> 5;
#pragma unroll
    for (int i = 0; i < 32; i += 8)
        tile[ty + i][tx] = qkvb[(size_t)(b * SS + sx + ty + i) * 256 + 128 + dy + tx];
    __syncthreads();
#pragma unroll
    for (int i = 0; i < 32; i += 8)
        Vtg[(size_t)(b * 64 + dy + ty + i) * SS + sx + tx] = tile[tx][ty + i];
}

// ---------------------------------------------------------------------------
// bf16 MFMA GEMM, BMx128 tile, BK=32, 256 thr = 4 waves.
// Round-2 post-mortem: conflicts are 0 but time unchanged -> the LDS pipe at
// conflict-free b128 throughput (~85 B/cyc/CU, m134) is the phase critical
// path. Only lever: LDS bytes per FLOP = (Mw+Nw)/(Mw*Nw) of the per-WAVE
// tile. So add BM=256 config: wave tile 128x64 (2x2 waves), ratio 42.7 vs
// 21.3 for the old 64x32 -> half the LDS reads per FLOP, and half the
// staging writes per CU (fewer blocks reload the same B panel).
//   BM=256: waves 2x2, wave 128x64, MT=8,NT=4, acc 128 VGPR, LDS 48KB dbuf
//   BM=128: waves 2x2, wave  64x64, MT=4,NT=4
//   BM=64 : waves 1x4, wave  64x32, MT=4,NT=2   (QKV / out-proj: small K)
// 16B-chunk XOR swizzle (round 1) kept: read slot q^((l16>>1)&3); inverse
// applied on global source (kcol) since global_load_lds writes linearly.
// LN folding / STATS / RESID / FOLD semantics unchanged.
// ---------------------------------------------------------------------------
__device__ __forceinline__ void async16(const void* g, void* l) {
    __builtin_amdgcn_global_load_lds(
        (const __attribute__((address_space(1))) void*)g,
        (__attribute__((address_space(3))) void*)l, 16, 0, 0);
}

template <bool RELU, bool RESID, bool STATS, bool FOLD, int BM>
__global__ __launch_bounds__(256) void gemm_mfma(const short* __restrict__ A,
                                                 const short* __restrict__ BT,
                                                 const float* __restrict__ bias,
                                                 const float* __restrict__ colsum,
                                                 const short* __restrict__ residB,
                                                 short* __restrict__ C,
                                                 const double* __restrict__ statsIn,
                                                 double* __restrict__ statsOut,
                                                 int M, int N, int K) {
    constexpr int MT = (BM == 256) ? 8 : 4;
    constexpr int NT = (BM == 64) ? 2 : 4;
    __shared__ short As[2][BM * 32];
    __shared__ short Bs[2][128 * 32];
    const int t   = threadIdx.x;
    const int wv  = t >> 6;
    const int l   = t & 63;
    const int q   = l >> 4,  l16 = l & 15;
    const int mbase = (BM == 256) ? (wv >> 1) * 128
                    : (BM == 128) ? (wv >> 1) * 64 : 0;
    const int nbase = (BM == 64) ? wv * 32 : (wv & 1) * 64;
    const long m0 = (long)blockIdx.x * BM;
    const long n0 = (long)blockIdx.y * 128;

    float muf = 0.f, rstdf = 1.f;
    if (FOLD || RESID) {
        if (statsIn) {
            double mean = statsIn[0] * (1.0 / NTOT);
            double var  = statsIn[1] * (1.0 / NTOT) - mean * mean;
            muf   = (float)mean;
            rstdf = (float)(1.0 / sqrt(var + LN_EPS));
        }
    }

    f32x4 acc[MT][NT] = {};

    const int srow = wv * 16 + (l >> 2);
    // Inverse-swizzled global chunk: lane fills LDS slot (l&3) of row
    // wv*16+(l>>2)+i*64; slot must hold chunk (l&3)^((row>>1)&3), and
    // (row>>1)&3 == (l>>3)&3 here (i*64, wv*16 vanish mod 4 after >>1).
    const int kcol = (((l & 3) ^ ((l >> 3) & 3)) * 8);
    // Read-side slot XOR: fragment row is mbase+i*16+l16 -> (row>>1)&3 ==
    // (l16>>1)&3 (mbase, i*16 vanish mod 4 after >>1).
    const int csw = (l16 >> 1) & 3;

    auto stage = [&](int buf, int k0) {
#pragma unroll
        for (int i = 0; i < BM / 64; ++i)
            async16(A + (m0 + srow + i * 64) * (long)K + k0 + kcol,
                    &As[buf][(wv * 16 + i * 64) * 32 + l * 8]);
#pragma unroll
        for (int i = 0; i < 2; ++i)
            async16(BT + (n0 + srow + i * 64) * (long)K + k0 + kcol,
                    &Bs[buf][(wv * 16 + i * 64) * 32 + l * 8]);
    };
    auto compute = [&](int buf) {
        short8 af[MT], bfr[NT];
#pragma unroll
        for (int i = 0; i < MT; ++i)
            af[i] = *(const short8*)&As[buf][(mbase + i * 16 + l16) * 32 + (q ^ csw) * 8];
#pragma unroll
        for (int i = 0; i < NT; ++i)
            bfr[i] = *(const short8*)&Bs[buf][(nbase + i * 16 + l16) * 32 + (q ^ csw) * 8];
#pragma unroll
        for (int mt = 0; mt < MT; ++mt)
#pragma unroll
            for (int nt = 0; nt < NT; ++nt)
                acc[mt][nt] = __builtin_amdgcn_mfma_f32_16x16x32_bf16(
                    af[mt], bfr[nt], acc[mt][nt], 0, 0, 0);
    };

    // prologue: fill buffer 0 with K-step 0
    stage(0, 0);
    __syncthreads();                 // drains vmcnt -> buf0 ready
    for (int k0 = 0; k0 < K; k0 += 64) {
        // prefetch next K-step into buf1 while computing buf0
        if (k0 + 32 < K) stage(1, k0 + 32);
        compute(0);
        __syncthreads();             // buf1 ready; buf0 reads done
        if (k0 + 64 < K) stage(0, k0 + 64);
        if (k0 + 32 < K) {
            compute(1);
            __syncthreads();         // buf0 ready; buf1 reads done
        }
    }

    const float mr = muf * rstdf;
    float s = 0.f, sq = 0.f;
#pragma unroll
    for (int mt = 0; mt < MT; ++mt) {
        const long rowb = m0 + mbase + mt * 16 + q * 4;
#pragma unroll
        for (int nt = 0; nt < NT; ++nt) {
            const long col = n0 + nbase + nt * 16 + l16;
            const float bv = bias[col];
            const float cs = FOLD ? colsum[col] : 0.f;
#pragma unroll
            for (int r = 0; r < 4; ++r) {
                const long idx = (rowb + r) * (long)N + col;
                float v = acc[mt][nt][r];
                if (FOLD) v = rstdf * v + bv - mr * cs;
                else      v = v + bv;
                if (RESID) v += (b2f(residB[idx]) - muf) * rstdf;
                if (RELU)  v = fmaxf(v, 0.0f);
                if (STATS) { s += v; sq += v * v; }
                C[idx] = f2b(v);
            }
        }
    }
    if (STATS) {
#pragma unroll
        for (int o = 32; o; o >>= 1) {
            s  += __shfl_down(s, o);
            sq += __shfl_down(sq, o);
        }
        float* sm = (float*)As;        // K-loop fully done; safe to reuse
        if (l == 0) { sm[wv] = s; sm[4 + wv] = sq; }
        __syncthreads();
        if (t == 0) {
            atomicAdd(&statsOut[0], (double)(sm[0] + sm[1] + sm[2] + sm[3]));
            atomicAdd(&statsOut[1], (double)(sm[4] + sm[5] + sm[6] + sm[7]));
        }
    }
}

// ---------------------------------------------------------------------------
// bf16 MFMA flash attention (unchanged).
// ---------------------------------------------------------------------------
__global__ __launch_bounds__(256) void attn_mfma(const short* __restrict__ qkvb,
                                                 const short* __restrict__ Vtg,
                                                 short* __restrict__ head) {
    const int b  = blockIdx.y;
    const int q0 = blockIdx.x * 64;
    const int t  = threadIdx.x;
    const int w  = t >> 6;
    const int l  = t & 63;
    const int l15 = l & 15, lq = l >> 4;
    const int l7  = l & 7,  l8 = l >> 3;

    __shared__ short Ks[64][72];
    __shared__ short Vs[64][72];
    __shared__ short Ps[4][16][68];

    short8 qf[2];
    {
        const short* qrow = qkvb + (size_t)(b * SS + q0 + w * 16 + l15) * 256;
        qf[0] = *(const short8*)(qrow + lq * 8);
        qf[1] = *(const short8*)(qrow + 32 + lq * 8);
    }

    f32x4 acc[4];
#pragma unroll
    for (int mt = 0; mt < 4; ++mt) acc[mt] = {0.f, 0.f, 0.f, 0.f};
    float m_i = -INFINITY, l_i = 0.f;
    const float sc = 0.0450712500463f;   // log2(e)/32

    short8 kreg[2], vreg[2];
    {
        const short* kb = qkvb + (size_t)(b * SS) * 256 + 64;
        kreg[0] = *(const short8*)(kb + (size_t)(w * 8 + l8) * 256 + l7 * 8);
        kreg[1] = *(const short8*)(kb + (size_t)(32 + w * 8 + l8) * 256 + l7 * 8);
        const short* vb = Vtg + (size_t)b * 64 * SS;
        vreg[0] = *(const short8*)(vb + (size_t)(w * 8 + l8) * SS + l7 * 8);
        vreg[1] = *(const short8*)(vb + (size_t)(32 + w * 8 + l8) * SS + l7 * 8);
    }

    for (int kt = 0; kt < SS / 64; ++kt) {
        __syncthreads();
        *(short8*)&Ks[w * 8 + l8][l7 * 8]      = kreg[0];
        *(short8*)&Ks[32 + w * 8 + l8][l7 * 8] = kreg[1];
        *(short8*)&Vs[w * 8 + l8][l7 * 8]      = vreg[0];
        *(short8*)&Vs[32 + w * 8 + l8][l7 * 8] = vreg[1];
        if (kt + 1 < SS / 64) {
            const short* kb = qkvb + (size_t)(b * SS + (kt + 1) * 64) * 256 + 64;
            kreg[0] = *(const short8*)(kb + (size_t)(w * 8 + l8) * 256 + l7 * 8);
            kreg[1] = *(const short8*)(kb + (size_t)(32 + w * 8 + l8) * 256 + l7 * 8);
            const short* vb = Vtg + (size_t)b * 64 * SS + (kt + 1) * 64;
            vreg[0] = *(const short8*)(vb + (size_t)(w * 8 + l8) * SS + l7 * 8);
            vreg[1] = *(const short8*)(vb + (size_t)(32 + w * 8 + l8) * SS + l7 * 8);
        }
        __syncthreads();

        f32x4 st[4];
#pragma unroll
        for (int mt = 0; mt < 4; ++mt) st[mt] = {0.f, 0.f, 0.f, 0.f};
#pragma unroll
        for (int kc = 0; kc < 2; ++kc)
#pragma unroll
            for (int mt = 0; mt < 4; ++mt) {
                short8 kf = *(const short8*)&Ks[mt * 16 + l15][kc * 32 + lq * 8];
                st[mt] = __builtin_amdgcn_mfma_f32_16x16x32_bf16(kf, qf[kc], st[mt], 0, 0, 0);
            }
        float mx = m_i;
#pragma unroll
        for (int mt = 0; mt < 4; ++mt)
#pragma unroll
            for (int r = 0; r < 4; ++r) {
                st[mt][r] *= sc;
                mx = fmaxf(mx, st[mt][r]);
            }
        mx = fmaxf(mx, __shfl_xor(mx, 16));
        mx = fmaxf(mx, __shfl_xor(mx, 32));
        float alpha = exp2f(m_i - mx);
        float rs = 0.f;
#pragma unroll
        for (int mt = 0; mt < 4; ++mt) {
            s16x4 pk;
#pragma unroll
            for (int r = 0; r < 4; ++r) {
                float p = exp2f(st[mt][r] - mx);
                rs += p;
                pk[r] = f2b(p);
            }
            *(s16x4*)&Ps[w][l15][mt * 16 + lq * 4] = pk;
        }
        rs += __shfl_xor(rs, 16);
        rs += __shfl_xor(rs, 32);
        l_i = l_i * alpha + rs;
        m_i = mx;
#pragma unroll
        for (int mt = 0; mt < 4; ++mt)
#pragma unroll
            for (int r = 0; r < 4; ++r) acc[mt][r] *= alpha;

#pragma unroll
        for (int kc = 0; kc < 2; ++kc) {
            s16x4 p0 = *(const s16x4*)&Ps[w][l15][kc * 32 + lq * 8];
            s16x4 p1 = *(const s16x4*)&Ps[w][l15][kc * 32 + lq * 8 + 4];
            short8 pf = __builtin_shufflevector(p0, p1, 0, 1, 2, 3, 4, 5, 6, 7);
#pragma unroll
            for (int mt = 0; mt < 4; ++mt) {
                short8 vf = *(const short8*)&Vs[mt * 16 + l15][kc * 32 + lq * 8];
                acc[mt] = __builtin_amdgcn_mfma_f32_16x16x32_bf16(vf, pf, acc[mt], 0, 0, 0);
            }
        }
    }
    float inv = 1.0f / l_i;
    short* out = head + (size_t)(b * SS + q0 + w * 16 + l15) * 64;
#pragma unroll
    for (int mt = 0; mt < 4; ++mt) {
        s16x4 o;
#pragma unroll
        for (int r = 0; r < 4; ++r) o[r] = f2b(acc[mt][r] * inv);
        *(s16x4*)&out[mt * 16 + lq * 4] = o;
    }
}

// ---------------------------------------------------------------------------
// Final LN2 normalize: d_out fp32 = (b2f(T1) - mu)*rstd
// ---------------------------------------------------------------------------
__global__ __launch_bounds__(256) void lnfinal_kernel(const short* __restrict__ y,
                                                      float* __restrict__ out,
                                                      const double* __restrict__ red,
                                                      int n) {
    double mean = red[0] / n;
    double var  = red[1] / n - mean * mean;
    float mu   = (float)mean;
    float rstd = (float)(1.0 / sqrt(var + LN_EPS));
    for (int i = blockIdx.x * blockDim.x + threadIdx.x; i < n;
         i += gridDim.x * blockDim.x)
        out[i] = (b2f(y[i]) - mu) * rstd;
}

// ---------------------------------------------------------------------------
extern "C" void kernel_launch(void* const* d_in, const int* in_sizes, int n_in,
                              void* d_out, int out_size, void* d_ws, size_t ws_size,
                              hipStream_t stream) {
    const int*   ids = (const int*)d_in[0];
    const float* emb = (const float*)d_in[1];
    const float* Wq  = (const float*)d_in[2];
    const float* bq  = (const float*)d_in[3];
    const float* Wk  = (const float*)d_in[4];
    const float* bk  = (const float*)d_in[5];
    const float* Wv  = (const float*)d_in[6];
    const float* bv  = (const float*)d_in[7];
    const float* Wo  = (const float*)d_in[8];
    const float* bo  = (const float*)d_in[9];
    const float* W1  = (const float*)d_in[10];
    const float* b1  = (const float*)d_in[11];
    const float* W2  = (const float*)d_in[12];
    const float* b2  = (const float*)d_in[13];

    float* xout = (float*)d_out;                     // final output only
    char* w = (char*)d_ws;

    // Buffers (bf16 unless noted):
    //   hch  [16384][2048] (full) or [8192][2048] (chunked) -- FF hidden
    //   qkvb [16384][256], Vtg [8][64][2048], head [16384][64]  (alias in hch)
    //   T1   trunk y (rep input / FF2 output), T2 trunk z (outproj output)
    const bool big = ws_size >= (size_t)105195712 + 256;

    short *qkvb, *Vtg, *head, *T1, *T2, *hch, *WqkvT, *WoST, *W1T, *W2T;
    float *bqkv, *csq, *csw1; double* red;

    if (big) {
        hch   = (short*)(w + 0);                     // 64 MB
        qkvb  = (short*)(w + 0);                     //  8 MB (alias)
        Vtg   = (short*)(w + 8388608);               //  2 MB (alias)
        head  = (short*)(w + 10485760);              //  2 MB (alias)
        T1    = (short*)(w + 67108864);              // 16 MB
        T2    = (short*)(w + 83886080);              // 16 MB
        WqkvT = (short*)(w + 100663296);
        bqkv  = (float*)(w + 100925440);
        csq   = (float*)(w + 100926464);
        WoST  = (short*)(w + 100927488);
        W1T   = (short*)(w + 100993024);
        csw1  = (float*)(w + 103090176);
        W2T   = (short*)(w + 103098368);
        red   = (double*)(w + 105195520);
    } else {
        hch   = (short*)(w + 0);                     // 32 MB (M=8192 chunks)
        qkvb  = (short*)(w + 0);
        Vtg   = (short*)(w + 8388608);
        head  = (short*)(w + 10485760);
        T1    = (short*)(w + 33554432);
        T2    = (short*)(w + 50331648);
        WqkvT = (short*)(w + 67108864);
        bqkv  = (float*)(w + 67371008);
        csq   = (float*)(w + 67372032);
        WoST  = (short*)(w + 67373056);
        W1T   = (short*)(w + 67438592);
        csw1  = (float*)(w + 69535744);
        W2T   = (short*)(w + 69543936);
        red   = (double*)(w + 71641088);
    }

    // ---- setup (once per launch) ----
    packqkvT_kernel<<<(256 * 512 + 255) / 256, 256, 0, stream>>>(Wq, Wk, Wv, bq, bk, bv, WqkvT, bqkv);
    wosumT_kernel<<<(512 * 64 + 255) / 256, 256, 0, stream>>>(Wo, WoST);
    transpose_b16<<<dim3(2048 / 32, 512 / 32), 256, 0, stream>>>(W1, W1T, 512, 2048);
    transpose_b16<<<dim3(512 / 32, 2048 / 32), 256, 0, stream>>>(W2, W2T, 2048, 512);
    colsum_kernel<<<9, 256, 0, stream>>>(WqkvT, W1T, csq, csw1);
    embed_kernel<<<NTOT / 256, 256, 0, stream>>>(ids, emb, T1, red);

    for (int rep = 0; rep < 6; ++rep) {
        const double* sprev = rep ? red + 4 * (rep - 1) + 2 : nullptr;  // LN2 stats of prev rep
        double* red1 = red + 4 * rep;        // LN1 stats (over z = outproj out)
        double* red2 = red + 4 * rep + 2;    // LN2 stats (over y' = FF2 out)

        // QKV: LN2-folded  qkvb = LN(T1) @ Wqkv + bqkv   [16384][256]
        gemm_mfma<false, false, false, true, 64><<<dim3(256, 2), 256, 0, stream>>>(
            T1, WqkvT, bqkv, csq, nullptr, qkvb, sprev, nullptr, ROWS, 256, DM);
        // V transpose
        vtrans_kernel<<<dim3(SS / 32, 2, BB), 256, 0, stream>>>(qkvb, Vtg);
        // flash attention -> head
        attn_mfma<<<dim3(SS / 64, BB), 256, 0, stream>>>(qkvb, Vtg, head);
        // out-proj: T2 = head @ WoS + bo + LN(T1); stats -> red1
        gemm_mfma<false, true, true, false, 64><<<dim3(256, 4), 256, 0, stream>>>(
            head, WoST, bo, nullptr, T1, T2, sprev, red1, ROWS, DM, DK);
        // FF (LN1 folded into FF1; resid LN1(T2) in FF2; stats -> red2)
        if (big) {
            gemm_mfma<true, false, false, true, 256><<<dim3(64, 16), 256, 0, stream>>>(
                T2, W1T, b1, csw1, nullptr, hch, red1, nullptr, ROWS, DFF, DM);
            gemm_mfma<false, true, true, false, 256><<<dim3(64, 4), 256, 0, stream>>>(
                hch, W2T, b2, nullptr, T2, T1, red1, red2, ROWS, DM, DFF);
        } else {
            for (int c = 0; c < 2; ++c) {
                const size_t off = (size_t)c * 8192 * DM;
                gemm_mfma<true, false, false, true, 256><<<dim3(32, 16), 256, 0, stream>>>(
                    T2 + off, W1T, b1, csw1, nullptr, hch, red1, nullptr, 8192, DFF, DM);
                gemm_mfma<false, true, true, false, 256><<<dim3(32, 4), 256, 0, stream>>>(
                    hch, W2T, b2, nullptr, T2 + off, T1 + off, red1, red2, 8192, DM, DFF);
            }
        }
    }
    // final LN2 normalize -> fp32 output
    lnfinal_kernel<<<4096, 256, 0, stream>>>(T1, xout, red + 4 * 5 + 2, NTOT);
}

// Round 4
// 1432.388 us; speedup vs baseline: 1.2328x; 1.2328x over previous
//
#include <hip/hip_runtime.h>
#include <math.h>

// Problem constants
#define BB 8
#define SS 2048
#define DM 512
#define DK 64
#define DFF 2048
#define ROWS (BB*SS)          // 16384
#define NTOT (ROWS*DM)        // 8388608
#define LN_EPS 1e-5
#define PAD_IDX 0

typedef __attribute__((ext_vector_type(8))) short short8;
typedef __attribute__((ext_vector_type(4))) short s16x4;
typedef __attribute__((ext_vector_type(4))) float f32x4;

__device__ __forceinline__ short f2b(float f) {        // fp32 -> bf16 (RNE)
    unsigned u = __float_as_uint(f);
    unsigned r = (u + 0x7fffu + ((u >> 16) & 1u)) >> 16;
    return (short)r;
}
__device__ __forceinline__ float b2f(short s) {        // bf16 -> fp32
    return __uint_as_float(((unsigned)(unsigned short)s) << 16);
}

// ---------------------------------------------------------------------------
// Embedding + positional encoding -> trunk T1 (bf16); zero LN stat slots
// ---------------------------------------------------------------------------
__global__ __launch_bounds__(256) void embed_kernel(const int* __restrict__ ids,
                                                    const float* __restrict__ emb,
                                                    short* __restrict__ T1,
                                                    double* __restrict__ red) {
    int idx = blockIdx.x * 256 + threadIdx.x;
    if (idx < 24) red[idx] = 0.0;              // 12 LN slots x (sum,sumsq)
    if (idx >= NTOT) return;
    int d   = idx & (DM - 1);
    int row = idx >> 9;
    int s   = row & (SS - 1);
    int id  = ids[row];
    float e = (id != PAD_IDX) ? emb[(size_t)id * DM + d] : 0.0f;
    float ex  = 2.0f * (float)d / 512.0f;
    float div = powf(10000.0f, ex);
    float arg = (float)s / div;
    float pe  = (d & 1) ? cosf(arg) : sinf(arg);
    T1[idx] = f2b(e + pe);
}

// ---------------------------------------------------------------------------
// Weight packing: WqkvT bf16 [256][512] (rows 192..255 zero) + bqkv fp32[256]
// ---------------------------------------------------------------------------
__global__ __launch_bounds__(256) void packqkvT_kernel(const float* __restrict__ Wq,
                                                       const float* __restrict__ Wk,
                                                       const float* __restrict__ Wv,
                                                       const float* __restrict__ bq,
                                                       const float* __restrict__ bk,
                                                       const float* __restrict__ bv,
                                                       short* __restrict__ WqkvT,
                                                       float* __restrict__ bqkv) {
    int i = blockIdx.x * 256 + threadIdx.x;
    if (i < 256 * 512) {
        int n = i >> 9, k = i & 511;
        float v = (n < 64)  ? Wq[k * 64 + n]
                : (n < 128) ? Wk[k * 64 + (n - 64)]
                : (n < 192) ? Wv[k * 64 + (n - 128)] : 0.0f;
        WqkvT[i] = f2b(v);
    }
    if (i < 256)
        bqkv[i] = (i < 64) ? bq[i] : (i < 128) ? bk[i - 64] : (i < 192) ? bv[i - 128] : 0.0f;
}

// WoST bf16 [512][64]: WoST[e][k] = sum_h Wo[h*64+k][e]
__global__ __launch_bounds__(256) void wosumT_kernel(const float* __restrict__ Wo,
                                                     short* __restrict__ WoST) {
    int i = blockIdx.x * 256 + threadIdx.x;
    if (i >= 512 * 64) return;
    int e = i >> 6, k = i & 63;
    float s = 0.f;
#pragma unroll
    for (int h = 0; h < 8; ++h) s += Wo[(size_t)(h * 64 + k) * 512 + e];
    WoST[i] = f2b(s);
}

// Tiled transpose fp32[R][C] -> bf16[C][R]
__global__ __launch_bounds__(256) void transpose_b16(const float* __restrict__ in,
                                                     short* __restrict__ out,
                                                     int R, int C) {
    __shared__ float tile[32][33];
    int bx = blockIdx.x * 32;
    int by = blockIdx.y * 32;
    int tx = threadIdx.x & 31, ty = threadIdx.x >> 5;
#pragma unroll
    for (int i = 0; i < 32; i += 8)
        tile[ty + i][tx] = in[(size_t)(by + ty + i) * C + bx + tx];
    __syncthreads();
#pragma unroll
    for (int i = 0; i < 32; i += 8)
        out[(size_t)(bx + ty + i) * R + by + tx] = f2b(tile[tx][ty + i]);
}

// Column sums of bf16 weights (for LN folding):
// csq[n<256] = sum_k WqkvT[n][k]; csw1[n<2048] = sum_k W1T[n][k]
__global__ __launch_bounds__(256) void colsum_kernel(const short* __restrict__ WqkvT,
                                                     const short* __restrict__ W1T,
                                                     float* __restrict__ csq,
                                                     float* __restrict__ csw1) {
    int i = blockIdx.x * 256 + threadIdx.x;
    if (i < 256) {
        const short* p = WqkvT + (size_t)i * 512;
        float s = 0.f;
        for (int k = 0; k < 512; ++k) s += b2f(p[k]);
        csq[i] = s;
    } else if (i < 2304) {
        int n = i - 256;
        const short* p = W1T + (size_t)n * 512;
        float s = 0.f;
        for (int k = 0; k < 512; ++k) s += b2f(p[k]);
        csw1[n] = s;
    }
}

// V slice of qkvb [16384][256] -> Vtg bf16 [8][64][2048]
__global__ __launch_bounds__(256) void vtrans_kernel(const short* __restrict__ qkvb,
                                                     short* __restrict__ Vtg) {
    __shared__ short tile[32][40];
    int sx = blockIdx.x * 32;
    int dy = blockIdx.y * 32;
    int b  = blockIdx.z;
    int tx = threadIdx.x & 31, ty = threadIdx.x >> 5;
#pragma unroll
    for (int i = 0; i < 32; i += 8)
        tile[ty + i][tx] = qkvb[(size_t)(b * SS + sx + ty + i) * 256 + 128 + dy + tx];
    __syncthreads();
#pragma unroll
    for (int i = 0; i < 32; i += 8)
        Vtg[(size_t)(b * 64 + dy + ty + i) * SS + sx + tx] = tile[tx][ty + i];
}

// ---------------------------------------------------------------------------
// bf16 MFMA GEMM, BMx128 tile (BM=128 or 64), BK=32, 256 thr = 4 waves.
// Round-3 post-mortem: BM=256 regressed (VGPR 168 -> 2 blocks/CU); dbuf with
// __syncthreads was null because the compiler's barrier drains vmcnt(0) --
// including the just-issued prefetch (the m97 structural stall). This round:
// COUNTED-vmcnt pipeline over RAW barriers (T3/T4 minimum):
//   prologue: stage tile0, tile1 (2L loads/lane in flight)
//   per 32-K step:
//     s_waitcnt vmcnt(L)   <- oldest tile landed; newer L stay in flight
//     s_barrier            <- all waves passed their waitcnt => tile in LDS
//     ds_read fragments; s_waitcnt lgkmcnt(0); sched_barrier(0)  [rule #18]
//     s_barrier            <- all waves done reading => WAR-safe
//     stage(this buf, tile i+2)     <- back to 2L in flight
//     setprio(1); MFMA; setprio(0)  [T5]
// Loads get a full step (~790 cyc) of latency budget instead of ~0.
// 16B-chunk XOR swizzle (round 1, conflicts=0) kept: read slot q^((l16>>1)&3),
// inverse on global source since global_load_lds writes linearly.
// LN folding / STATS / RESID / FOLD semantics unchanged.
// ---------------------------------------------------------------------------
__device__ __forceinline__ void async16(const void* g, void* l) {
    __builtin_amdgcn_global_load_lds(
        (const __attribute__((address_space(1))) void*)g,
        (__attribute__((address_space(3))) void*)l, 16, 0, 0);
}

template <bool RELU, bool RESID, bool STATS, bool FOLD, int BM>
__global__ __launch_bounds__(256) void gemm_mfma(const short* __restrict__ A,
                                                 const short* __restrict__ BT,
                                                 const float* __restrict__ bias,
                                                 const float* __restrict__ colsum,
                                                 const short* __restrict__ residB,
                                                 short* __restrict__ C,
                                                 const double* __restrict__ statsIn,
                                                 double* __restrict__ statsOut,
                                                 int M, int N, int K) {
    constexpr int NT = (BM == 128) ? 4 : 2;
    __shared__ short As[2][BM * 32];
    __shared__ short Bs[2][128 * 32];
    const int t   = threadIdx.x;
    const int wv  = t >> 6;
    const int l   = t & 63;
    const int q   = l >> 4,  l16 = l & 15;
    const int mbase = (BM == 128) ? (wv >> 1) * 64 : 0;
    const int nbase = (BM == 128) ? (wv & 1) * 64 : wv * 32;
    const long m0 = (long)blockIdx.x * BM;
    const long n0 = (long)blockIdx.y * 128;

    float muf = 0.f, rstdf = 1.f;
    if (FOLD || RESID) {
        if (statsIn) {
            double mean = statsIn[0] * (1.0 / NTOT);
            double var  = statsIn[1] * (1.0 / NTOT) - mean * mean;
            muf   = (float)mean;
            rstdf = (float)(1.0 / sqrt(var + LN_EPS));
        }
    }

    f32x4 acc[4][NT] = {};

    const int srow = wv * 16 + (l >> 2);
    // Inverse-swizzled global chunk: lane fills LDS slot (l&3) of row
    // wv*16+(l>>2)+i*64; slot must hold chunk (l&3)^((row>>1)&3), and
    // (row>>1)&3 == (l>>3)&3 here (i*64, wv*16 vanish mod 4 after >>1).
    const int kcol = (((l & 3) ^ ((l >> 3) & 3)) * 8);
    // Read-side slot XOR: fragment row is mbase+i*16+l16 -> (row>>1)&3 ==
    // (l16>>1)&3 (mbase, i*16 vanish mod 4 after >>1).
    const int csw = (l16 >> 1) & 3;

    auto stage = [&](int buf, int k0) {
#pragma unroll
        for (int i = 0; i < BM / 64; ++i)
            async16(A + (m0 + srow + i * 64) * (long)K + k0 + kcol,
                    &As[buf][(wv * 16 + i * 64) * 32 + l * 8]);
#pragma unroll
        for (int i = 0; i < 2; ++i)
            async16(BT + (n0 + srow + i * 64) * (long)K + k0 + kcol,
                    &Bs[buf][(wv * 16 + i * 64) * 32 + l * 8]);
    };

    // prologue: two tiles in flight (all call sites have K >= 64)
    stage(0, 0);
    stage(1, 32);
    int cur = 0;
    for (int k0 = 0; k0 < K; k0 += 32) {
        // counted wait: current tile landed; next tile's L loads stay in flight
        if (k0 + 32 < K) {
            if constexpr (BM == 128) asm volatile("s_waitcnt vmcnt(4)" ::: "memory");
            else                     asm volatile("s_waitcnt vmcnt(3)" ::: "memory");
        } else {
            asm volatile("s_waitcnt vmcnt(0)" ::: "memory");
        }
        __builtin_amdgcn_sched_barrier(0);
        __builtin_amdgcn_s_barrier();          // tile[cur] fully in LDS
        __builtin_amdgcn_sched_barrier(0);

        short8 af[4], bfr[NT];
#pragma unroll
        for (int i = 0; i < 4; ++i)
            af[i] = *(const short8*)&As[cur][(mbase + i * 16 + l16) * 32 + (q ^ csw) * 8];
#pragma unroll
        for (int i = 0; i < NT; ++i)
            bfr[i] = *(const short8*)&Bs[cur][(nbase + i * 16 + l16) * 32 + (q ^ csw) * 8];
        asm volatile("s_waitcnt lgkmcnt(0)" ::: "memory");
        __builtin_amdgcn_sched_barrier(0);
        __builtin_amdgcn_s_barrier();          // all reads done -> WAR-safe
        __builtin_amdgcn_sched_barrier(0);

        if (k0 + 64 < K) stage(cur, k0 + 64);  // re-stage this buffer, tile i+2

        __builtin_amdgcn_s_setprio(1);
#pragma unroll
        for (int mt = 0; mt < 4; ++mt)
#pragma unroll
            for (int nt = 0; nt < NT; ++nt)
                acc[mt][nt] = __builtin_amdgcn_mfma_f32_16x16x32_bf16(
                    af[mt], bfr[nt], acc[mt][nt], 0, 0, 0);
        __builtin_amdgcn_s_setprio(0);
        cur ^= 1;
    }

    const float mr = muf * rstdf;
    float s = 0.f, sq = 0.f;
#pragma unroll
    for (int mt = 0; mt < 4; ++mt) {
        const long rowb = m0 + mbase + mt * 16 + q * 4;
#pragma unroll
        for (int nt = 0; nt < NT; ++nt) {
            const long col = n0 + nbase + nt * 16 + l16;
            const float bv = bias[col];
            const float cs = FOLD ? colsum[col] : 0.f;
#pragma unroll
            for (int r = 0; r < 4; ++r) {
                const long idx = (rowb + r) * (long)N + col;
                float v = acc[mt][nt][r];
                if (FOLD) v = rstdf * v + bv - mr * cs;
                else      v = v + bv;
                if (RESID) v += (b2f(residB[idx]) - muf) * rstdf;
                if (RELU)  v = fmaxf(v, 0.0f);
                if (STATS) { s += v; sq += v * v; }
                C[idx] = f2b(v);
            }
        }
    }
    if (STATS) {
#pragma unroll
        for (int o = 32; o; o >>= 1) {
            s  += __shfl_down(s, o);
            sq += __shfl_down(sq, o);
        }
        float* sm = (float*)As;        // K-loop fully done; safe to reuse
        if (l == 0) { sm[wv] = s; sm[4 + wv] = sq; }
        __syncthreads();
        if (t == 0) {
            atomicAdd(&statsOut[0], (double)(sm[0] + sm[1] + sm[2] + sm[3]));
            atomicAdd(&statsOut[1], (double)(sm[4] + sm[5] + sm[6] + sm[7]));
        }
    }
}

// ---------------------------------------------------------------------------
// bf16 MFMA flash attention (unchanged).
// ---------------------------------------------------------------------------
__global__ __launch_bounds__(256) void attn_mfma(const short* __restrict__ qkvb,
                                                 const short* __restrict__ Vtg,
                                                 short* __restrict__ head) {
    const int b  = blockIdx.y;
    const int q0 = blockIdx.x * 64;
    const int t  = threadIdx.x;
    const int w  = t >> 6;
    const int l  = t & 63;
    const int l15 = l & 15, lq = l >> 4;
    const int l7  = l & 7,  l8 = l >> 3;

    __shared__ short Ks[64][72];
    __shared__ short Vs[64][72];
    __shared__ short Ps[4][16][68];

    short8 qf[2];
    {
        const short* qrow = qkvb + (size_t)(b * SS + q0 + w * 16 + l15) * 256;
        qf[0] = *(const short8*)(qrow + lq * 8);
        qf[1] = *(const short8*)(qrow + 32 + lq * 8);
    }

    f32x4 acc[4];
#pragma unroll
    for (int mt = 0; mt < 4; ++mt) acc[mt] = {0.f, 0.f, 0.f, 0.f};
    float m_i = -INFINITY, l_i = 0.f;
    const float sc = 0.0450712500463f;   // log2(e)/32

    short8 kreg[2], vreg[2];
    {
        const short* kb = qkvb + (size_t)(b * SS) * 256 + 64;
        kreg[0] = *(const short8*)(kb + (size_t)(w * 8 + l8) * 256 + l7 * 8);
        kreg[1] = *(const short8*)(kb + (size_t)(32 + w * 8 + l8) * 256 + l7 * 8);
        const short* vb = Vtg + (size_t)b * 64 * SS;
        vreg[0] = *(const short8*)(vb + (size_t)(w * 8 + l8) * SS + l7 * 8);
        vreg[1] = *(const short8*)(vb + (size_t)(32 + w * 8 + l8) * SS + l7 * 8);
    }

    for (int kt = 0; kt < SS / 64; ++kt) {
        __syncthreads();
        *(short8*)&Ks[w * 8 + l8][l7 * 8]      = kreg[0];
        *(short8*)&Ks[32 + w * 8 + l8][l7 * 8] = kreg[1];
        *(short8*)&Vs[w * 8 + l8][l7 * 8]      = vreg[0];
        *(short8*)&Vs[32 + w * 8 + l8][l7 * 8] = vreg[1];
        if (kt + 1 < SS / 64) {
            const short* kb = qkvb + (size_t)(b * SS + (kt + 1) * 64) * 256 + 64;
            kreg[0] = *(const short8*)(kb + (size_t)(w * 8 + l8) * 256 + l7 * 8);
            kreg[1] = *(const short8*)(kb + (size_t)(32 + w * 8 + l8) * 256 + l7 * 8);
            const short* vb = Vtg + (size_t)b * 64 * SS + (kt + 1) * 64;
            vreg[0] = *(const short8*)(vb + (size_t)(w * 8 + l8) * SS + l7 * 8);
            vreg[1] = *(const short8*)(vb + (size_t)(32 + w * 8 + l8) * SS + l7 * 8);
        }
        __syncthreads();

        f32x4 st[4];
#pragma unroll
        for (int mt = 0; mt < 4; ++mt) st[mt] = {0.f, 0.f, 0.f, 0.f};
#pragma unroll
        for (int kc = 0; kc < 2; ++kc)
#pragma unroll
            for (int mt = 0; mt < 4; ++mt) {
                short8 kf = *(const short8*)&Ks[mt * 16 + l15][kc * 32 + lq * 8];
                st[mt] = __builtin_amdgcn_mfma_f32_16x16x32_bf16(kf, qf[kc], st[mt], 0, 0, 0);
            }
        float mx = m_i;
#pragma unroll
        for (int mt = 0; mt < 4; ++mt)
#pragma unroll
            for (int r = 0; r < 4; ++r) {
                st[mt][r] *= sc;
                mx = fmaxf(mx, st[mt][r]);
            }
        mx = fmaxf(mx, __shfl_xor(mx, 16));
        mx = fmaxf(mx, __shfl_xor(mx, 32));
        float alpha = exp2f(m_i - mx);
        float rs = 0.f;
#pragma unroll
        for (int mt = 0; mt < 4; ++mt) {
            s16x4 pk;
#pragma unroll
            for (int r = 0; r < 4; ++r) {
                float p = exp2f(st[mt][r] - mx);
                rs += p;
                pk[r] = f2b(p);
            }
            *(s16x4*)&Ps[w][l15][mt * 16 + lq * 4] = pk;
        }
        rs += __shfl_xor(rs, 16);
        rs += __shfl_xor(rs, 32);
        l_i = l_i * alpha + rs;
        m_i = mx;
#pragma unroll
        for (int mt = 0; mt < 4; ++mt)
#pragma unroll
            for (int r = 0; r < 4; ++r) acc[mt][r] *= alpha;

#pragma unroll
        for (int kc = 0; kc < 2; ++kc) {
            s16x4 p0 = *(const s16x4*)&Ps[w][l15][kc * 32 + lq * 8];
            s16x4 p1 = *(const s16x4*)&Ps[w][l15][kc * 32 + lq * 8 + 4];
            short8 pf = __builtin_shufflevector(p0, p1, 0, 1, 2, 3, 4, 5, 6, 7);
#pragma unroll
            for (int mt = 0; mt < 4; ++mt) {
                short8 vf = *(const short8*)&Vs[mt * 16 + l15][kc * 32 + lq * 8];
                acc[mt] = __builtin_amdgcn_mfma_f32_16x16x32_bf16(vf, pf, acc[mt], 0, 0, 0);
            }
        }
    }
    float inv = 1.0f / l_i;
    short* out = head + (size_t)(b * SS + q0 + w * 16 + l15) * 64;
#pragma unroll
    for (int mt = 0; mt < 4; ++mt) {
        s16x4 o;
#pragma unroll
        for (int r = 0; r < 4; ++r) o[r] = f2b(acc[mt][r] * inv);
        *(s16x4*)&out[mt * 16 + lq * 4] = o;
    }
}

// ---------------------------------------------------------------------------
// Final LN2 normalize: d_out fp32 = (b2f(T1) - mu)*rstd
// ---------------------------------------------------------------------------
__global__ __launch_bounds__(256) void lnfinal_kernel(const short* __restrict__ y,
                                                      float* __restrict__ out,
                                                      const double* __restrict__ red,
                                                      int n) {
    double mean = red[0] / n;
    double var  = red[1] / n - mean * mean;
    float mu   = (float)mean;
    float rstd = (float)(1.0 / sqrt(var + LN_EPS));
    for (int i = blockIdx.x * blockDim.x + threadIdx.x; i < n;
         i += gridDim.x * blockDim.x)
        out[i] = (b2f(y[i]) - mu) * rstd;
}

// ---------------------------------------------------------------------------
extern "C" void kernel_launch(void* const* d_in, const int* in_sizes, int n_in,
                              void* d_out, int out_size, void* d_ws, size_t ws_size,
                              hipStream_t stream) {
    const int*   ids = (const int*)d_in[0];
    const float* emb = (const float*)d_in[1];
    const float* Wq  = (const float*)d_in[2];
    const float* bq  = (const float*)d_in[3];
    const float* Wk  = (const float*)d_in[4];
    const float* bk  = (const float*)d_in[5];
    const float* Wv  = (const float*)d_in[6];
    const float* bv  = (const float*)d_in[7];
    const float* Wo  = (const float*)d_in[8];
    const float* bo  = (const float*)d_in[9];
    const float* W1  = (const float*)d_in[10];
    const float* b1  = (const float*)d_in[11];
    const float* W2  = (const float*)d_in[12];
    const float* b2  = (const float*)d_in[13];

    float* xout = (float*)d_out;                     // final output only
    char* w = (char*)d_ws;

    // Buffers (bf16 unless noted):
    //   hch  [16384][2048] (full) or [8192][2048] (chunked) -- FF hidden
    //   qkvb [16384][256], Vtg [8][64][2048], head [16384][64]  (alias in hch)
    //   T1   trunk y (rep input / FF2 output), T2 trunk z (outproj output)
    const bool big = ws_size >= (size_t)105195712 + 256;

    short *qkvb, *Vtg, *head, *T1, *T2, *hch, *WqkvT, *WoST, *W1T, *W2T;
    float *bqkv, *csq, *csw1; double* red;

    if (big) {
        hch   = (short*)(w + 0);                     // 64 MB
        qkvb  = (short*)(w + 0);                     //  8 MB (alias)
        Vtg   = (short*)(w + 8388608);               //  2 MB (alias)
        head  = (short*)(w + 10485760);              //  2 MB (alias)
        T1    = (short*)(w + 67108864);              // 16 MB
        T2    = (short*)(w + 83886080);              // 16 MB
        WqkvT = (short*)(w + 100663296);
        bqkv  = (float*)(w + 100925440);
        csq   = (float*)(w + 100926464);
        WoST  = (short*)(w + 100927488);
        W1T   = (short*)(w + 100993024);
        csw1  = (float*)(w + 103090176);
        W2T   = (short*)(w + 103098368);
        red   = (double*)(w + 105195520);
    } else {
        hch   = (short*)(w + 0);                     // 32 MB (M=8192 chunks)
        qkvb  = (short*)(w + 0);
        Vtg   = (short*)(w + 8388608);
        head  = (short*)(w + 10485760);
        T1    = (short*)(w + 33554432);
        T2    = (short*)(w + 50331648);
        WqkvT = (short*)(w + 67108864);
        bqkv  = (float*)(w + 67371008);
        csq   = (float*)(w + 67372032);
        WoST  = (short*)(w + 67373056);
        W1T   = (short*)(w + 67438592);
        csw1  = (float*)(w + 69535744);
        W2T   = (short*)(w + 69543936);
        red   = (double*)(w + 71641088);
    }

    // ---- setup (once per launch) ----
    packqkvT_kernel<<<(256 * 512 + 255) / 256, 256, 0, stream>>>(Wq, Wk, Wv, bq, bk, bv, WqkvT, bqkv);
    wosumT_kernel<<<(512 * 64 + 255) / 256, 256, 0, stream>>>(Wo, WoST);
    transpose_b16<<<dim3(2048 / 32, 512 / 32), 256, 0, stream>>>(W1, W1T, 512, 2048);
    transpose_b16<<<dim3(512 / 32, 2048 / 32), 256, 0, stream>>>(W2, W2T, 2048, 512);
    colsum_kernel<<<9, 256, 0, stream>>>(WqkvT, W1T, csq, csw1);
    embed_kernel<<<NTOT / 256, 256, 0, stream>>>(ids, emb, T1, red);

    for (int rep = 0; rep < 6; ++rep) {
        const double* sprev = rep ? red + 4 * (rep - 1) + 2 : nullptr;  // LN2 stats of prev rep
        double* red1 = red + 4 * rep;        // LN1 stats (over z = outproj out)
        double* red2 = red + 4 * rep + 2;    // LN2 stats (over y' = FF2 out)

        // QKV: LN2-folded  qkvb = LN(T1) @ Wqkv + bqkv   [16384][256]
        gemm_mfma<false, false, false, true, 64><<<dim3(256, 2), 256, 0, stream>>>(
            T1, WqkvT, bqkv, csq, nullptr, qkvb, sprev, nullptr, ROWS, 256, DM);
        // V transpose
        vtrans_kernel<<<dim3(SS / 32, 2, BB), 256, 0, stream>>>(qkvb, Vtg);
        // flash attention -> head
        attn_mfma<<<dim3(SS / 64, BB), 256, 0, stream>>>(qkvb, Vtg, head);
        // out-proj: T2 = head @ WoS + bo + LN(T1); stats -> red1
        gemm_mfma<false, true, true, false, 64><<<dim3(256, 4), 256, 0, stream>>>(
            head, WoST, bo, nullptr, T1, T2, sprev, red1, ROWS, DM, DK);
        // FF (LN1 folded into FF1; resid LN1(T2) in FF2; stats -> red2)
        if (big) {
            gemm_mfma<true, false, false, true, 128><<<dim3(128, 16), 256, 0, stream>>>(
                T2, W1T, b1, csw1, nullptr, hch, red1, nullptr, ROWS, DFF, DM);
            gemm_mfma<false, true, true, false, 64><<<dim3(256, 4), 256, 0, stream>>>(
                hch, W2T, b2, nullptr, T2, T1, red1, red2, ROWS, DM, DFF);
        } else {
            for (int c = 0; c < 2; ++c) {
                const size_t off = (size_t)c * 8192 * DM;
                gemm_mfma<true, false, false, true, 128><<<dim3(64, 16), 256, 0, stream>>>(
                    T2 + off, W1T, b1, csw1, nullptr, hch, red1, nullptr, 8192, DFF, DM);
                gemm_mfma<false, true, true, false, 64><<<dim3(128, 4), 256, 0, stream>>>(
                    hch, W2T, b2, nullptr, T2 + off, T1 + off, red1, red2, 8192, DM, DFF);
            }
        }
    }
    // final LN2 normalize -> fp32 output
    lnfinal_kernel<<<4096, 256, 0, stream>>>(T1, xout, red + 4 * 5 + 2, NTOT);
}

// Round 5
// 1370.268 us; speedup vs baseline: 1.2887x; 1.0453x over previous
//
#include <hip/hip_runtime.h>
#include <math.h>

// Problem constants
#define BB 8
#define SS 2048
#define DM 512
#define DK 64
#define DFF 2048
#define ROWS (BB*SS)          // 16384
#define NTOT (ROWS*DM)        // 8388608
#define LN_EPS 1e-5
#define PAD_IDX 0

typedef __attribute__((ext_vector_type(8))) short short8;
typedef __attribute__((ext_vector_type(4))) short s16x4;
typedef __attribute__((ext_vector_type(4))) float f32x4;

__device__ __forceinline__ short f2b(float f) {        // fp32 -> bf16 (RNE)
    unsigned u = __float_as_uint(f);
    unsigned r = (u + 0x7fffu + ((u >> 16) & 1u)) >> 16;
    return (short)r;
}
__device__ __forceinline__ float b2f(short s) {        // bf16 -> fp32
    return __uint_as_float(((unsigned)(unsigned short)s) << 16);
}

// ---------------------------------------------------------------------------
// Embedding + positional encoding -> trunk T1 (bf16); zero LN stat slots
// ---------------------------------------------------------------------------
__global__ __launch_bounds__(256) void embed_kernel(const int* __restrict__ ids,
                                                    const float* __restrict__ emb,
                                                    short* __restrict__ T1,
                                                    double* __restrict__ red) {
    int idx = blockIdx.x * 256 + threadIdx.x;
    if (idx < 24) red[idx] = 0.0;              // 12 LN slots x (sum,sumsq)
    if (idx >= NTOT) return;
    int d   = idx & (DM - 1);
    int row = idx >> 9;
    int s   = row & (SS - 1);
    int id  = ids[row];
    float e = (id != PAD_IDX) ? emb[(size_t)id * DM + d] : 0.0f;
    float ex  = 2.0f * (float)d / 512.0f;
    float div = powf(10000.0f, ex);
    float arg = (float)s / div;
    float pe  = (d & 1) ? cosf(arg) : sinf(arg);
    T1[idx] = f2b(e + pe);
}

// ---------------------------------------------------------------------------
// Weight packing: WqkvT bf16 [256][512] (rows 192..255 zero) + bqkv fp32[256]
// ---------------------------------------------------------------------------
__global__ __launch_bounds__(256) void packqkvT_kernel(const float* __restrict__ Wq,
                                                       const float* __restrict__ Wk,
                                                       const float* __restrict__ Wv,
                                                       const float* __restrict__ bq,
                                                       const float* __restrict__ bk,
                                                       const float* __restrict__ bv,
                                                       short* __restrict__ WqkvT,
                                                       float* __restrict__ bqkv) {
    int i = blockIdx.x * 256 + threadIdx.x;
    if (i < 256 * 512) {
        int n = i >> 9, k = i & 511;
        float v = (n < 64)  ? Wq[k * 64 + n]
                : (n < 128) ? Wk[k * 64 + (n - 64)]
                : (n < 192) ? Wv[k * 64 + (n - 128)] : 0.0f;
        WqkvT[i] = f2b(v);
    }
    if (i < 256)
        bqkv[i] = (i < 64) ? bq[i] : (i < 128) ? bk[i - 64] : (i < 192) ? bv[i - 128] : 0.0f;
}

// WoST bf16 [512][64]: WoST[e][k] = sum_h Wo[h*64+k][e]
__global__ __launch_bounds__(256) void wosumT_kernel(const float* __restrict__ Wo,
                                                     short* __restrict__ WoST) {
    int i = blockIdx.x * 256 + threadIdx.x;
    if (i >= 512 * 64) return;
    int e = i >> 6, k = i & 63;
    float s = 0.f;
#pragma unroll
    for (int h = 0; h < 8; ++h) s += Wo[(size_t)(h * 64 + k) * 512 + e];
    WoST[i] = f2b(s);
}

// Tiled transpose fp32[R][C] -> bf16[C][R]
__global__ __launch_bounds__(256) void transpose_b16(const float* __restrict__ in,
                                                     short* __restrict__ out,
                                                     int R, int C) {
    __shared__ float tile[32][33];
    int bx = blockIdx.x * 32;
    int by = blockIdx.y * 32;
    int tx = threadIdx.x & 31, ty = threadIdx.x >> 5;
#pragma unroll
    for (int i = 0; i < 32; i += 8)
        tile[ty + i][tx] = in[(size_t)(by + ty + i) * C + bx + tx];
    __syncthreads();
#pragma unroll
    for (int i = 0; i < 32; i += 8)
        out[(size_t)(bx + ty + i) * R + by + tx] = f2b(tile[tx][ty + i]);
}

// Column sums of bf16 weights (for LN folding):
// csq[n<256] = sum_k WqkvT[n][k]; csw1[n<2048] = sum_k W1T[n][k]
__global__ __launch_bounds__(256) void colsum_kernel(const short* __restrict__ WqkvT,
                                                     const short* __restrict__ W1T,
                                                     float* __restrict__ csq,
                                                     float* __restrict__ csw1) {
    int i = blockIdx.x * 256 + threadIdx.x;
    if (i < 256) {
        const short* p = WqkvT + (size_t)i * 512;
        float s = 0.f;
        for (int k = 0; k < 512; ++k) s += b2f(p[k]);
        csq[i] = s;
    } else if (i < 2304) {
        int n = i - 256;
        const short* p = W1T + (size_t)n * 512;
        float s = 0.f;
        for (int k = 0; k < 512; ++k) s += b2f(p[k]);
        csw1[n] = s;
    }
}

// V slice of qkvb [16384][256] -> Vtg bf16 [8][64][2048]
__global__ __launch_bounds__(256) void vtrans_kernel(const short* __restrict__ qkvb,
                                                     short* __restrict__ Vtg) {
    __shared__ short tile[32][40];
    int sx = blockIdx.x * 32;
    int dy = blockIdx.y * 32;
    int b  = blockIdx.z;
    int tx = threadIdx.x & 31, ty = threadIdx.x >> 5;
#pragma unroll
    for (int i = 0; i < 32; i += 8)
        tile[ty + i][tx] = qkvb[(size_t)(b * SS + sx + ty + i) * 256 + 128 + dy + tx];
    __syncthreads();
#pragma unroll
    for (int i = 0; i < 32; i += 8)
        Vtg[(size_t)(b * 64 + dy + ty + i) * SS + sx + tx] = tile[tx][ty + i];
}

// ---------------------------------------------------------------------------
// bf16 MFMA GEMM, BMx128 tile, BK in {32,64}, 256 thr = 4 waves.
// Round-4 post-mortem: counted-vmcnt pipeline helped modestly (84->81.5us);
// remaining ~400cyc/step is FIXED per-step cost (barrier lockstep skew +
// lgkmcnt(0) LDS latency + stage setup), paid 64x at BK=32. This round:
// BK=64 for BM=64 call sites -> half the steps, same fixed cost per step,
// 2x work per step (16 MFMA, 12 ds_read). LDS 48KB dbuf -> 3 blocks/CU
// (effective occupancy was ~2.6 anyway). FF1 keeps BM=128/BK=32 (BK=64
// there would need 64KB -> 2 blocks/CU, round-3 regression mode).
// Layouts:
//  BK=32: row stride 32 sh; lane->row wv*16+(l>>2), chunk l&3;
//         read slot q^((l16>>1)&3); source chunk (l&3)^((l>>3)&3).
//  BK=64: row stride 64 sh; lane->row wv*8+(l>>3), chunk l&7;
//         read slot (ks*4+q)^(l16&7); source chunk (l&7)^((l>>3)&7).
// Both: inverse swizzle pre-applied on the GLOBAL source address
// (global_load_lds writes linearly); reads use the swizzled slot ->
// uniform bank spread, conflicts ~0 (verified round 2).
// Pipeline per BK-step: vmcnt(LPS)->barrier->ds_read all->lgkmcnt(0)->
// sched_barrier->barrier->re-stage(+2)->setprio(1) MFMA setprio(0).
// LN folding / STATS / RESID / FOLD semantics unchanged.
// ---------------------------------------------------------------------------
__device__ __forceinline__ void async16(const void* g, void* l) {
    __builtin_amdgcn_global_load_lds(
        (const __attribute__((address_space(1))) void*)g,
        (__attribute__((address_space(3))) void*)l, 16, 0, 0);
}

template <bool RELU, bool RESID, bool STATS, bool FOLD, int BM, int BK>
__global__ __launch_bounds__(256) void gemm_mfma(const short* __restrict__ A,
                                                 const short* __restrict__ BT,
                                                 const float* __restrict__ bias,
                                                 const float* __restrict__ colsum,
                                                 const short* __restrict__ residB,
                                                 short* __restrict__ C,
                                                 const double* __restrict__ statsIn,
                                                 double* __restrict__ statsOut,
                                                 int M, int N, int K) {
    constexpr int NT   = (BM == 128) ? 4 : 2;
    constexpr int KSUB = BK / 32;                    // 32-K sub-steps per tile
    constexpr int RPS  = (BK == 32) ? 64 : 32;       // rows per stage unit (256 lanes)
    constexpr int LPS  = BM / RPS + 128 / RPS;       // loads/lane per staged tile
    __shared__ short As[2][BM * BK];
    __shared__ short Bs[2][128 * BK];
    const int t   = threadIdx.x;
    const int wv  = t >> 6;
    const int l   = t & 63;
    const int q   = l >> 4,  l16 = l & 15;
    const int mbase = (BM == 128) ? (wv >> 1) * 64 : 0;
    const int nbase = (BM == 128) ? (wv & 1) * 64 : wv * 32;
    const long m0 = (long)blockIdx.x * BM;
    const long n0 = (long)blockIdx.y * 128;

    float muf = 0.f, rstdf = 1.f;
    if (FOLD || RESID) {
        if (statsIn) {
            double mean = statsIn[0] * (1.0 / NTOT);
            double var  = statsIn[1] * (1.0 / NTOT) - mean * mean;
            muf   = (float)mean;
            rstdf = (float)(1.0 / sqrt(var + LN_EPS));
        }
    }

    f32x4 acc[4][NT] = {};

    // staging geometry (see header comment)
    const int srow = (BK == 32) ? (wv * 16 + (l >> 2)) : (wv * 8 + (l >> 3));
    const int kcol = (BK == 32) ? (((l & 3) ^ ((l >> 3) & 3)) * 8)
                                : (((l & 7) ^ ((l >> 3) & 7)) * 8);
    const int wrow = (BK == 32) ? wv * 16 : wv * 8;  // wave's LDS base row

    auto stage = [&](int buf, int k0) {
#pragma unroll
        for (int i = 0; i < BM / RPS; ++i)
            async16(A + (m0 + srow + i * RPS) * (long)K + k0 + kcol,
                    &As[buf][(wrow + i * RPS) * BK + l * 8]);
#pragma unroll
        for (int i = 0; i < 128 / RPS; ++i)
            async16(BT + (n0 + srow + i * RPS) * (long)K + k0 + kcol,
                    &Bs[buf][(wrow + i * RPS) * BK + l * 8]);
    };

    // prologue: up to two tiles in flight
    stage(0, 0);
    if (K > BK) stage(1, BK);
    int cur = 0;
    for (int k0 = 0; k0 < K; k0 += BK) {
        // counted wait: current tile landed; next tile's LPS loads stay in flight
        if (k0 + BK < K) {
            if constexpr (LPS == 3)      asm volatile("s_waitcnt vmcnt(3)" ::: "memory");
            else if constexpr (LPS == 4) asm volatile("s_waitcnt vmcnt(4)" ::: "memory");
            else                         asm volatile("s_waitcnt vmcnt(6)" ::: "memory");
        } else {
            asm volatile("s_waitcnt vmcnt(0)" ::: "memory");
        }
        __builtin_amdgcn_sched_barrier(0);
        __builtin_amdgcn_s_barrier();          // tile[cur] fully in LDS
        __builtin_amdgcn_sched_barrier(0);

        short8 af[KSUB][4], bfr[KSUB][NT];
#pragma unroll
        for (int ks = 0; ks < KSUB; ++ks) {
            const int slot = (BK == 32) ? (q ^ ((l16 >> 1) & 3))
                                        : ((ks * 4 + q) ^ (l16 & 7));
#pragma unroll
            for (int i = 0; i < 4; ++i)
                af[ks][i] = *(const short8*)&As[cur][(mbase + i * 16 + l16) * BK + slot * 8];
#pragma unroll
            for (int i = 0; i < NT; ++i)
                bfr[ks][i] = *(const short8*)&Bs[cur][(nbase + i * 16 + l16) * BK + slot * 8];
        }
        asm volatile("s_waitcnt lgkmcnt(0)" ::: "memory");
        __builtin_amdgcn_sched_barrier(0);
        __builtin_amdgcn_s_barrier();          // all reads done -> WAR-safe
        __builtin_amdgcn_sched_barrier(0);

        if (k0 + 2 * BK < K) stage(cur, k0 + 2 * BK);  // re-stage, tile i+2

        __builtin_amdgcn_s_setprio(1);
#pragma unroll
        for (int ks = 0; ks < KSUB; ++ks)
#pragma unroll
            for (int mt = 0; mt < 4; ++mt)
#pragma unroll
                for (int nt = 0; nt < NT; ++nt)
                    acc[mt][nt] = __builtin_amdgcn_mfma_f32_16x16x32_bf16(
                        af[ks][mt], bfr[ks][nt], acc[mt][nt], 0, 0, 0);
        __builtin_amdgcn_s_setprio(0);
        cur ^= 1;
    }

    const float mr = muf * rstdf;
    float s = 0.f, sq = 0.f;
#pragma unroll
    for (int mt = 0; mt < 4; ++mt) {
        const long rowb = m0 + mbase + mt * 16 + q * 4;
#pragma unroll
        for (int nt = 0; nt < NT; ++nt) {
            const long col = n0 + nbase + nt * 16 + l16;
            const float bv = bias[col];
            const float cs = FOLD ? colsum[col] : 0.f;
#pragma unroll
            for (int r = 0; r < 4; ++r) {
                const long idx = (rowb + r) * (long)N + col;
                float v = acc[mt][nt][r];
                if (FOLD) v = rstdf * v + bv - mr * cs;
                else      v = v + bv;
                if (RESID) v += (b2f(residB[idx]) - muf) * rstdf;
                if (RELU)  v = fmaxf(v, 0.0f);
                if (STATS) { s += v; sq += v * v; }
                C[idx] = f2b(v);
            }
        }
    }
    if (STATS) {
#pragma unroll
        for (int o = 32; o; o >>= 1) {
            s  += __shfl_down(s, o);
            sq += __shfl_down(sq, o);
        }
        float* sm = (float*)As;        // K-loop fully done; safe to reuse
        if (l == 0) { sm[wv] = s; sm[4 + wv] = sq; }
        __syncthreads();
        if (t == 0) {
            atomicAdd(&statsOut[0], (double)(sm[0] + sm[1] + sm[2] + sm[3]));
            atomicAdd(&statsOut[1], (double)(sm[4] + sm[5] + sm[6] + sm[7]));
        }
    }
}

// ---------------------------------------------------------------------------
// bf16 MFMA flash attention (unchanged).
// ---------------------------------------------------------------------------
__global__ __launch_bounds__(256) void attn_mfma(const short* __restrict__ qkvb,
                                                 const short* __restrict__ Vtg,
                                                 short* __restrict__ head) {
    const int b  = blockIdx.y;
    const int q0 = blockIdx.x * 64;
    const int t  = threadIdx.x;
    const int w  = t >> 6;
    const int l  = t & 63;
    const int l15 = l & 15, lq = l >> 4;
    const int l7  = l & 7,  l8 = l >> 3;

    __shared__ short Ks[64][72];
    __shared__ short Vs[64][72];
    __shared__ short Ps[4][16][68];

    short8 qf[2];
    {
        const short* qrow = qkvb + (size_t)(b * SS + q0 + w * 16 + l15) * 256;
        qf[0] = *(const short8*)(qrow + lq * 8);
        qf[1] = *(const short8*)(qrow + 32 + lq * 8);
    }

    f32x4 acc[4];
#pragma unroll
    for (int mt = 0; mt < 4; ++mt) acc[mt] = {0.f, 0.f, 0.f, 0.f};
    float m_i = -INFINITY, l_i = 0.f;
    const float sc = 0.0450712500463f;   // log2(e)/32

    short8 kreg[2], vreg[2];
    {
        const short* kb = qkvb + (size_t)(b * SS) * 256 + 64;
        kreg[0] = *(const short8*)(kb + (size_t)(w * 8 + l8) * 256 + l7 * 8);
        kreg[1] = *(const short8*)(kb + (size_t)(32 + w * 8 + l8) * 256 + l7 * 8);
        const short* vb = Vtg + (size_t)b * 64 * SS;
        vreg[0] = *(const short8*)(vb + (size_t)(w * 8 + l8) * SS + l7 * 8);
        vreg[1] = *(const short8*)(vb + (size_t)(32 + w * 8 + l8) * SS + l7 * 8);
    }

    for (int kt = 0; kt < SS / 64; ++kt) {
        __syncthreads();
        *(short8*)&Ks[w * 8 + l8][l7 * 8]      = kreg[0];
        *(short8*)&Ks[32 + w * 8 + l8][l7 * 8] = kreg[1];
        *(short8*)&Vs[w * 8 + l8][l7 * 8]      = vreg[0];
        *(short8*)&Vs[32 + w * 8 + l8][l7 * 8] = vreg[1];
        if (kt + 1 < SS / 64) {
            const short* kb = qkvb + (size_t)(b * SS + (kt + 1) * 64) * 256 + 64;
            kreg[0] = *(const short8*)(kb + (size_t)(w * 8 + l8) * 256 + l7 * 8);
            kreg[1] = *(const short8*)(kb + (size_t)(32 + w * 8 + l8) * 256 + l7 * 8);
            const short* vb = Vtg + (size_t)b * 64 * SS + (kt + 1) * 64;
            vreg[0] = *(const short8*)(vb + (size_t)(w * 8 + l8) * SS + l7 * 8);
            vreg[1] = *(const short8*)(vb + (size_t)(32 + w * 8 + l8) * SS + l7 * 8);
        }
        __syncthreads();

        f32x4 st[4];
#pragma unroll
        for (int mt = 0; mt < 4; ++mt) st[mt] = {0.f, 0.f, 0.f, 0.f};
#pragma unroll
        for (int kc = 0; kc < 2; ++kc)
#pragma unroll
            for (int mt = 0; mt < 4; ++mt) {
                short8 kf = *(const short8*)&Ks[mt * 16 + l15][kc * 32 + lq * 8];
                st[mt] = __builtin_amdgcn_mfma_f32_16x16x32_bf16(kf, qf[kc], st[mt], 0, 0, 0);
            }
        float mx = m_i;
#pragma unroll
        for (int mt = 0; mt < 4; ++mt)
#pragma unroll
            for (int r = 0; r < 4; ++r) {
                st[mt][r] *= sc;
                mx = fmaxf(mx, st[mt][r]);
            }
        mx = fmaxf(mx, __shfl_xor(mx, 16));
        mx = fmaxf(mx, __shfl_xor(mx, 32));
        float alpha = exp2f(m_i - mx);
        float rs = 0.f;
#pragma unroll
        for (int mt = 0; mt < 4; ++mt) {
            s16x4 pk;
#pragma unroll
            for (int r = 0; r < 4; ++r) {
                float p = exp2f(st[mt][r] - mx);
                rs += p;
                pk[r] = f2b(p);
            }
            *(s16x4*)&Ps[w][l15][mt * 16 + lq * 4] = pk;
        }
        rs += __shfl_xor(rs, 16);
        rs += __shfl_xor(rs, 32);
        l_i = l_i * alpha + rs;
        m_i = mx;
#pragma unroll
        for (int mt = 0; mt < 4; ++mt)
#pragma unroll
            for (int r = 0; r < 4; ++r) acc[mt][r] *= alpha;

#pragma unroll
        for (int kc = 0; kc < 2; ++kc) {
            s16x4 p0 = *(const s16x4*)&Ps[w][l15][kc * 32 + lq * 8];
            s16x4 p1 = *(const s16x4*)&Ps[w][l15][kc * 32 + lq * 8 + 4];
            short8 pf = __builtin_shufflevector(p0, p1, 0, 1, 2, 3, 4, 5, 6, 7);
#pragma unroll
            for (int mt = 0; mt < 4; ++mt) {
                short8 vf = *(const short8*)&Vs[mt * 16 + l15][kc * 32 + lq * 8];
                acc[mt] = __builtin_amdgcn_mfma_f32_16x16x32_bf16(vf, pf, acc[mt], 0, 0, 0);
            }
        }
    }
    float inv = 1.0f / l_i;
    short* out = head + (size_t)(b * SS + q0 + w * 16 + l15) * 64;
#pragma unroll
    for (int mt = 0; mt < 4; ++mt) {
        s16x4 o;
#pragma unroll
        for (int r = 0; r < 4; ++r) o[r] = f2b(acc[mt][r] * inv);
        *(s16x4*)&out[mt * 16 + lq * 4] = o;
    }
}

// ---------------------------------------------------------------------------
// Final LN2 normalize: d_out fp32 = (b2f(T1) - mu)*rstd
// ---------------------------------------------------------------------------
__global__ __launch_bounds__(256) void lnfinal_kernel(const short* __restrict__ y,
                                                      float* __restrict__ out,
                                                      const double* __restrict__ red,
                                                      int n) {
    double mean = red[0] / n;
    double var  = red[1] / n - mean * mean;
    float mu   = (float)mean;
    float rstd = (float)(1.0 / sqrt(var + LN_EPS));
    for (int i = blockIdx.x * blockDim.x + threadIdx.x; i < n;
         i += gridDim.x * blockDim.x)
        out[i] = (b2f(y[i]) - mu) * rstd;
}

// ---------------------------------------------------------------------------
extern "C" void kernel_launch(void* const* d_in, const int* in_sizes, int n_in,
                              void* d_out, int out_size, void* d_ws, size_t ws_size,
                              hipStream_t stream) {
    const int*   ids = (const int*)d_in[0];
    const float* emb = (const float*)d_in[1];
    const float* Wq  = (const float*)d_in[2];
    const float* bq  = (const float*)d_in[3];
    const float* Wk  = (const float*)d_in[4];
    const float* bk  = (const float*)d_in[5];
    const float* Wv  = (const float*)d_in[6];
    const float* bv  = (const float*)d_in[7];
    const float* Wo  = (const float*)d_in[8];
    const float* bo  = (const float*)d_in[9];
    const float* W1  = (const float*)d_in[10];
    const float* b1  = (const float*)d_in[11];
    const float* W2  = (const float*)d_in[12];
    const float* b2  = (const float*)d_in[13];

    float* xout = (float*)d_out;                     // final output only
    char* w = (char*)d_ws;

    // Buffers (bf16 unless noted):
    //   hch  [16384][2048] (full) or [8192][2048] (chunked) -- FF hidden
    //   qkvb [16384][256], Vtg [8][64][2048], head [16384][64]  (alias in hch)
    //   T1   trunk y (rep input / FF2 output), T2 trunk z (outproj output)
    const bool big = ws_size >= (size_t)105195712 + 256;

    short *qkvb, *Vtg, *head, *T1, *T2, *hch, *WqkvT, *WoST, *W1T, *W2T;
    float *bqkv, *csq, *csw1; double* red;

    if (big) {
        hch   = (short*)(w + 0);                     // 64 MB
        qkvb  = (short*)(w + 0);                     //  8 MB (alias)
        Vtg   = (short*)(w + 8388608);               //  2 MB (alias)
        head  = (short*)(w + 10485760);              //  2 MB (alias)
        T1    = (short*)(w + 67108864);              // 16 MB
        T2    = (short*)(w + 83886080);              // 16 MB
        WqkvT = (short*)(w + 100663296);
        bqkv  = (float*)(w + 100925440);
        csq   = (float*)(w + 100926464);
        WoST  = (short*)(w + 100927488);
        W1T   = (short*)(w + 100993024);
        csw1  = (float*)(w + 103090176);
        W2T   = (short*)(w + 103098368);
        red   = (double*)(w + 105195520);
    } else {
        hch   = (short*)(w + 0);                     // 32 MB (M=8192 chunks)
        qkvb  = (short*)(w + 0);
        Vtg   = (short*)(w + 8388608);
        head  = (short*)(w + 10485760);
        T1    = (short*)(w + 33554432);
        T2    = (short*)(w + 50331648);
        WqkvT = (short*)(w + 67108864);
        bqkv  = (float*)(w + 67371008);
        csq   = (float*)(w + 67372032);
        WoST  = (short*)(w + 67373056);
        W1T   = (short*)(w + 67438592);
        csw1  = (float*)(w + 69535744);
        W2T   = (short*)(w + 69543936);
        red   = (double*)(w + 71641088);
    }

    // ---- setup (once per launch) ----
    packqkvT_kernel<<<(256 * 512 + 255) / 256, 256, 0, stream>>>(Wq, Wk, Wv, bq, bk, bv, WqkvT, bqkv);
    wosumT_kernel<<<(512 * 64 + 255) / 256, 256, 0, stream>>>(Wo, WoST);
    transpose_b16<<<dim3(2048 / 32, 512 / 32), 256, 0, stream>>>(W1, W1T, 512, 2048);
    transpose_b16<<<dim3(512 / 32, 2048 / 32), 256, 0, stream>>>(W2, W2T, 2048, 512);
    colsum_kernel<<<9, 256, 0, stream>>>(WqkvT, W1T, csq, csw1);
    embed_kernel<<<NTOT / 256, 256, 0, stream>>>(ids, emb, T1, red);

    for (int rep = 0; rep < 6; ++rep) {
        const double* sprev = rep ? red + 4 * (rep - 1) + 2 : nullptr;  // LN2 stats of prev rep
        double* red1 = red + 4 * rep;        // LN1 stats (over z = outproj out)
        double* red2 = red + 4 * rep + 2;    // LN2 stats (over y' = FF2 out)

        // QKV: LN2-folded  qkvb = LN(T1) @ Wqkv + bqkv   [16384][256]
        gemm_mfma<false, false, false, true, 64, 64><<<dim3(256, 2), 256, 0, stream>>>(
            T1, WqkvT, bqkv, csq, nullptr, qkvb, sprev, nullptr, ROWS, 256, DM);
        // V transpose
        vtrans_kernel<<<dim3(SS / 32, 2, BB), 256, 0, stream>>>(qkvb, Vtg);
        // flash attention -> head
        attn_mfma<<<dim3(SS / 64, BB), 256, 0, stream>>>(qkvb, Vtg, head);
        // out-proj: T2 = head @ WoS + bo + LN(T1); stats -> red1
        gemm_mfma<false, true, true, false, 64, 64><<<dim3(256, 4), 256, 0, stream>>>(
            head, WoST, bo, nullptr, T1, T2, sprev, red1, ROWS, DM, DK);
        // FF (LN1 folded into FF1; resid LN1(T2) in FF2; stats -> red2)
        if (big) {
            gemm_mfma<true, false, false, true, 128, 32><<<dim3(128, 16), 256, 0, stream>>>(
                T2, W1T, b1, csw1, nullptr, hch, red1, nullptr, ROWS, DFF, DM);
            gemm_mfma<false, true, true, false, 64, 64><<<dim3(256, 4), 256, 0, stream>>>(
                hch, W2T, b2, nullptr, T2, T1, red1, red2, ROWS, DM, DFF);
        } else {
            for (int c = 0; c < 2; ++c) {
                const size_t off = (size_t)c * 8192 * DM;
                gemm_mfma<true, false, false, true, 128, 32><<<dim3(64, 16), 256, 0, stream>>>(
                    T2 + off, W1T, b1, csw1, nullptr, hch, red1, nullptr, 8192, DFF, DM);
                gemm_mfma<false, true, true, false, 64, 64><<<dim3(128, 4), 256, 0, stream>>>(
                    hch, W2T, b2, nullptr, T2 + off, T1 + off, red1, red2, 8192, DM, DFF);
            }
        }
    }
    // final LN2 normalize -> fp32 output
    lnfinal_kernel<<<4096, 256, 0, stream>>>(T1, xout, red + 4 * 5 + 2, NTOT);
}

// Round 6
// 1200.396 us; speedup vs baseline: 1.4711x; 1.1415x over previous
//
#include <hip/hip_runtime.h>
#include <math.h>

// Problem constants
#define BB 8
#define SS 2048
#define DM 512
#define DK 64
#define DFF 2048
#define ROWS (BB*SS)          // 16384
#define NTOT (ROWS*DM)        // 8388608
#define LN_EPS 1e-5
#define PAD_IDX 0

typedef __attribute__((ext_vector_type(8))) short short8;
typedef __attribute__((ext_vector_type(4))) short s16x4;
typedef __attribute__((ext_vector_type(4))) float f32x4;

__device__ __forceinline__ short f2b(float f) {        // fp32 -> bf16 (RNE)
    unsigned u = __float_as_uint(f);
    unsigned r = (u + 0x7fffu + ((u >> 16) & 1u)) >> 16;
    return (short)r;
}
__device__ __forceinline__ float b2f(short s) {        // bf16 -> fp32
    return __uint_as_float(((unsigned)(unsigned short)s) << 16);
}

// ---------------------------------------------------------------------------
// Embedding + positional encoding -> trunk T1 (bf16); zero LN stat slots
// ---------------------------------------------------------------------------
__global__ __launch_bounds__(256) void embed_kernel(const int* __restrict__ ids,
                                                    const float* __restrict__ emb,
                                                    short* __restrict__ T1,
                                                    double* __restrict__ red) {
    int idx = blockIdx.x * 256 + threadIdx.x;
    if (idx < 24) red[idx] = 0.0;              // 12 LN slots x (sum,sumsq)
    if (idx >= NTOT) return;
    int d   = idx & (DM - 1);
    int row = idx >> 9;
    int s   = row & (SS - 1);
    int id  = ids[row];
    float e = (id != PAD_IDX) ? emb[(size_t)id * DM + d] : 0.0f;
    float ex  = 2.0f * (float)d / 512.0f;
    float div = powf(10000.0f, ex);
    float arg = (float)s / div;
    float pe  = (d & 1) ? cosf(arg) : sinf(arg);
    T1[idx] = f2b(e + pe);
}

// ---------------------------------------------------------------------------
// Weight packing: WqkvT bf16 [256][512] (rows 192..255 zero) + bqkv fp32[256]
// ---------------------------------------------------------------------------
__global__ __launch_bounds__(256) void packqkvT_kernel(const float* __restrict__ Wq,
                                                       const float* __restrict__ Wk,
                                                       const float* __restrict__ Wv,
                                                       const float* __restrict__ bq,
                                                       const float* __restrict__ bk,
                                                       const float* __restrict__ bv,
                                                       short* __restrict__ WqkvT,
                                                       float* __restrict__ bqkv) {
    int i = blockIdx.x * 256 + threadIdx.x;
    if (i < 256 * 512) {
        int n = i >> 9, k = i & 511;
        float v = (n < 64)  ? Wq[k * 64 + n]
                : (n < 128) ? Wk[k * 64 + (n - 64)]
                : (n < 192) ? Wv[k * 64 + (n - 128)] : 0.0f;
        WqkvT[i] = f2b(v);
    }
    if (i < 256)
        bqkv[i] = (i < 64) ? bq[i] : (i < 128) ? bk[i - 64] : (i < 192) ? bv[i - 128] : 0.0f;
}

// WoST bf16 [512][64]: WoST[e][k] = sum_h Wo[h*64+k][e]
__global__ __launch_bounds__(256) void wosumT_kernel(const float* __restrict__ Wo,
                                                     short* __restrict__ WoST) {
    int i = blockIdx.x * 256 + threadIdx.x;
    if (i >= 512 * 64) return;
    int e = i >> 6, k = i & 63;
    float s = 0.f;
#pragma unroll
    for (int h = 0; h < 8; ++h) s += Wo[(size_t)(h * 64 + k) * 512 + e];
    WoST[i] = f2b(s);
}

// Tiled transpose fp32[R][C] -> bf16[C][R]
__global__ __launch_bounds__(256) void transpose_b16(const float* __restrict__ in,
                                                     short* __restrict__ out,
                                                     int R, int C) {
    __shared__ float tile[32][33];
    int bx = blockIdx.x * 32;
    int by = blockIdx.y * 32;
    int tx = threadIdx.x & 31, ty = threadIdx.x >> 5;
#pragma unroll
    for (int i = 0; i < 32; i += 8)
        tile[ty + i][tx] = in[(size_t)(by + ty + i) * C + bx + tx];
    __syncthreads();
#pragma unroll
    for (int i = 0; i < 32; i += 8)
        out[(size_t)(bx + ty + i) * R + by + tx] = f2b(tile[tx][ty + i]);
}

// Column sums of bf16 weights (for LN folding):
// csq[n<256] = sum_k WqkvT[n][k]; csw1[n<2048] = sum_k W1T[n][k]
__global__ __launch_bounds__(256) void colsum_kernel(const short* __restrict__ WqkvT,
                                                     const short* __restrict__ W1T,
                                                     float* __restrict__ csq,
                                                     float* __restrict__ csw1) {
    int i = blockIdx.x * 256 + threadIdx.x;
    if (i < 256) {
        const short* p = WqkvT + (size_t)i * 512;
        float s = 0.f;
        for (int k = 0; k < 512; ++k) s += b2f(p[k]);
        csq[i] = s;
    } else if (i < 2304) {
        int n = i - 256;
        const short* p = W1T + (size_t)n * 512;
        float s = 0.f;
        for (int k = 0; k < 512; ++k) s += b2f(p[k]);
        csw1[n] = s;
    }
}

// V slice of qkvb [16384][256] -> Vtg bf16 [8][64][2048]
__global__ __launch_bounds__(256) void vtrans_kernel(const short* __restrict__ qkvb,
                                                     short* __restrict__ Vtg) {
    __shared__ short tile[32][40];
    int sx = blockIdx.x * 32;
    int dy = blockIdx.y * 32;
    int b  = blockIdx.z;
    int tx = threadIdx.x & 31, ty = threadIdx.x >> 5;
#pragma unroll
    for (int i = 0; i < 32; i += 8)
        tile[ty + i][tx] = qkvb[(size_t)(b * SS + sx + ty + i) * 256 + 128 + dy + tx];
    __syncthreads();
#pragma unroll
    for (int i = 0; i < 32; i += 8)
        Vtg[(size_t)(b * 64 + dy + ty + i) * SS + sx + tx] = tile[tx][ty + i];
}

// ---------------------------------------------------------------------------
// bf16 MFMA GEMM, BMxBN tile, BK in {32,64}, 256 thr = 4 waves.
// Round-5 post-mortem: FF2 at BK=64 is LDS-throughput bound: per-CU traffic
// 4 blk x 32 steps x 72KB = 9.2MB ~ 40us at ~90B/cyc, plus a residency tail
// (3-of-4 blocks/CU). Lever = per-wave tile efficiency (LDS B/FLOP ~
// (Mw+Nw)/(Mw*Nw)) + exact-residency grids:
//   FF2: BM=64, BN=256 (wave 64x64, NT=4): 6.7MB/CU, LDS 80KB -> 2 blk/CU,
//        grid 512 = exactly 2/CU (zero tail); A re-read 2x not 4x.
//   FF1: BM=128, BN=128, BK=64 (wave 64x64): steps 16->8, 6.1MB/CU.
// Wave layout: BM=128: 2x2 (mbase=(wv>>1)*64, nbase=(wv&1)*64);
//              BM=64,BN=256: 1x4 (nbase=wv*64); BM=64,BN=128: 1x4 (nbase=wv*32).
// BK=64 layout: row stride 64sh; stage lane->row wv*8+(l>>3), chunk l&7,
// source chunk pre-swizzled (l&7)^((l>>3)&7); read slot (ks*4+q)^(l16&7).
// (row&7 == l16&7 for all fragment rows since mbase/nbase/i*16 are mult of 16;
// conflicts measured 0 in round 5.)
// Pipeline per BK-step (T3/T4): vmcnt(LPS)->barrier->ds_read->lgkmcnt(0)->
// sched_barrier->barrier->re-stage(+2)->setprio(1) MFMA setprio(0).
// LN folding / STATS / RESID / FOLD semantics unchanged.
// ---------------------------------------------------------------------------
__device__ __forceinline__ void async16(const void* g, void* l) {
    __builtin_amdgcn_global_load_lds(
        (const __attribute__((address_space(1))) void*)g,
        (__attribute__((address_space(3))) void*)l, 16, 0, 0);
}

template <bool RELU, bool RESID, bool STATS, bool FOLD, int BM, int BN, int BK>
__global__ __launch_bounds__(256) void gemm_mfma(const short* __restrict__ A,
                                                 const short* __restrict__ BT,
                                                 const float* __restrict__ bias,
                                                 const float* __restrict__ colsum,
                                                 const short* __restrict__ residB,
                                                 short* __restrict__ C,
                                                 const double* __restrict__ statsIn,
                                                 double* __restrict__ statsOut,
                                                 int M, int N, int K) {
    constexpr int NT   = (BN == 256) ? 4 : ((BM == 128) ? 4 : 2);
    constexpr int KSUB = BK / 32;                    // 32-K sub-steps per tile
    constexpr int RPS  = (BK == 32) ? 64 : 32;       // rows per stage unit (256 lanes)
    constexpr int LPS  = (BM + BN) / RPS;            // loads/lane per staged tile
    __shared__ short As[2][BM * BK];
    __shared__ short Bs[2][BN * BK];
    const int t   = threadIdx.x;
    const int wv  = t >> 6;
    const int l   = t & 63;
    const int q   = l >> 4,  l16 = l & 15;
    const int mbase = (BM == 128) ? (wv >> 1) * 64 : 0;
    const int nbase = (BM == 128) ? (wv & 1) * 64
                    : ((BN == 256) ? wv * 64 : wv * 32);
    const long m0 = (long)blockIdx.x * BM;
    const long n0 = (long)blockIdx.y * BN;

    float muf = 0.f, rstdf = 1.f;
    if (FOLD || RESID) {
        if (statsIn) {
            double mean = statsIn[0] * (1.0 / NTOT);
            double var  = statsIn[1] * (1.0 / NTOT) - mean * mean;
            muf   = (float)mean;
            rstdf = (float)(1.0 / sqrt(var + LN_EPS));
        }
    }

    f32x4 acc[4][NT] = {};

    // staging geometry (see header comment)
    const int srow = (BK == 32) ? (wv * 16 + (l >> 2)) : (wv * 8 + (l >> 3));
    const int kcol = (BK == 32) ? (((l & 3) ^ ((l >> 3) & 3)) * 8)
                                : (((l & 7) ^ ((l >> 3) & 7)) * 8);
    const int wrow = (BK == 32) ? wv * 16 : wv * 8;  // wave's LDS base row

    auto stage = [&](int buf, int k0) {
#pragma unroll
        for (int i = 0; i < BM / RPS; ++i)
            async16(A + (m0 + srow + i * RPS) * (long)K + k0 + kcol,
                    &As[buf][(wrow + i * RPS) * BK + l * 8]);
#pragma unroll
        for (int i = 0; i < BN / RPS; ++i)
            async16(BT + (n0 + srow + i * RPS) * (long)K + k0 + kcol,
                    &Bs[buf][(wrow + i * RPS) * BK + l * 8]);
    };

    // prologue: up to two tiles in flight
    stage(0, 0);
    if (K > BK) stage(1, BK);
    int cur = 0;
    for (int k0 = 0; k0 < K; k0 += BK) {
        // counted wait: current tile landed; next tile's LPS loads stay in flight
        if (k0 + BK < K) {
            if constexpr (LPS == 3)       asm volatile("s_waitcnt vmcnt(3)" ::: "memory");
            else if constexpr (LPS == 4)  asm volatile("s_waitcnt vmcnt(4)" ::: "memory");
            else if constexpr (LPS == 6)  asm volatile("s_waitcnt vmcnt(6)" ::: "memory");
            else if constexpr (LPS == 8)  asm volatile("s_waitcnt vmcnt(8)" ::: "memory");
            else                          asm volatile("s_waitcnt vmcnt(10)" ::: "memory");
        } else {
            asm volatile("s_waitcnt vmcnt(0)" ::: "memory");
        }
        __builtin_amdgcn_sched_barrier(0);
        __builtin_amdgcn_s_barrier();          // tile[cur] fully in LDS
        __builtin_amdgcn_sched_barrier(0);

        short8 af[KSUB][4], bfr[KSUB][NT];
#pragma unroll
        for (int ks = 0; ks < KSUB; ++ks) {
            const int slot = (BK == 32) ? (q ^ ((l16 >> 1) & 3))
                                        : ((ks * 4 + q) ^ (l16 & 7));
#pragma unroll
            for (int i = 0; i < 4; ++i)
                af[ks][i] = *(const short8*)&As[cur][(mbase + i * 16 + l16) * BK + slot * 8];
#pragma unroll
            for (int i = 0; i < NT; ++i)
                bfr[ks][i] = *(const short8*)&Bs[cur][(nbase + i * 16 + l16) * BK + slot * 8];
        }
        asm volatile("s_waitcnt lgkmcnt(0)" ::: "memory");
        __builtin_amdgcn_sched_barrier(0);
        __builtin_amdgcn_s_barrier();          // all reads done -> WAR-safe
        __builtin_amdgcn_sched_barrier(0);

        if (k0 + 2 * BK < K) stage(cur, k0 + 2 * BK);  // re-stage, tile i+2

        __builtin_amdgcn_s_setprio(1);
#pragma unroll
        for (int ks = 0; ks < KSUB; ++ks)
#pragma unroll
            for (int mt = 0; mt < 4; ++mt)
#pragma unroll
                for (int nt = 0; nt < NT; ++nt)
                    acc[mt][nt] = __builtin_amdgcn_mfma_f32_16x16x32_bf16(
                        af[ks][mt], bfr[ks][nt], acc[mt][nt], 0, 0, 0);
        __builtin_amdgcn_s_setprio(0);
        cur ^= 1;
    }

    const float mr = muf * rstdf;
    float s = 0.f, sq = 0.f;
#pragma unroll
    for (int mt = 0; mt < 4; ++mt) {
        const long rowb = m0 + mbase + mt * 16 + q * 4;
#pragma unroll
        for (int nt = 0; nt < NT; ++nt) {
            const long col = n0 + nbase + nt * 16 + l16;
            const float bv = bias[col];
            const float cs = FOLD ? colsum[col] : 0.f;
#pragma unroll
            for (int r = 0; r < 4; ++r) {
                const long idx = (rowb + r) * (long)N + col;
                float v = acc[mt][nt][r];
                if (FOLD) v = rstdf * v + bv - mr * cs;
                else      v = v + bv;
                if (RESID) v += (b2f(residB[idx]) - muf) * rstdf;
                if (RELU)  v = fmaxf(v, 0.0f);
                if (STATS) { s += v; sq += v * v; }
                C[idx] = f2b(v);
            }
        }
    }
    if (STATS) {
#pragma unroll
        for (int o = 32; o; o >>= 1) {
            s  += __shfl_down(s, o);
            sq += __shfl_down(sq, o);
        }
        float* sm = (float*)As;        // K-loop fully done; safe to reuse
        if (l == 0) { sm[wv] = s; sm[4 + wv] = sq; }
        __syncthreads();
        if (t == 0) {
            atomicAdd(&statsOut[0], (double)(sm[0] + sm[1] + sm[2] + sm[3]));
            atomicAdd(&statsOut[1], (double)(sm[4] + sm[5] + sm[6] + sm[7]));
        }
    }
}

// ---------------------------------------------------------------------------
// bf16 MFMA flash attention (unchanged).
// ---------------------------------------------------------------------------
__global__ __launch_bounds__(256) void attn_mfma(const short* __restrict__ qkvb,
                                                 const short* __restrict__ Vtg,
                                                 short* __restrict__ head) {
    const int b  = blockIdx.y;
    const int q0 = blockIdx.x * 64;
    const int t  = threadIdx.x;
    const int w  = t >> 6;
    const int l  = t & 63;
    const int l15 = l & 15, lq = l >> 4;
    const int l7  = l & 7,  l8 = l >> 3;

    __shared__ short Ks[64][72];
    __shared__ short Vs[64][72];
    __shared__ short Ps[4][16][68];

    short8 qf[2];
    {
        const short* qrow = qkvb + (size_t)(b * SS + q0 + w * 16 + l15) * 256;
        qf[0] = *(const short8*)(qrow + lq * 8);
        qf[1] = *(const short8*)(qrow + 32 + lq * 8);
    }

    f32x4 acc[4];
#pragma unroll
    for (int mt = 0; mt < 4; ++mt) acc[mt] = {0.f, 0.f, 0.f, 0.f};
    float m_i = -INFINITY, l_i = 0.f;
    const float sc = 0.0450712500463f;   // log2(e)/32

    short8 kreg[2], vreg[2];
    {
        const short* kb = qkvb + (size_t)(b * SS) * 256 + 64;
        kreg[0] = *(const short8*)(kb + (size_t)(w * 8 + l8) * 256 + l7 * 8);
        kreg[1] = *(const short8*)(kb + (size_t)(32 + w * 8 + l8) * 256 + l7 * 8);
        const short* vb = Vtg + (size_t)b * 64 * SS;
        vreg[0] = *(const short8*)(vb + (size_t)(w * 8 + l8) * SS + l7 * 8);
        vreg[1] = *(const short8*)(vb + (size_t)(32 + w * 8 + l8) * SS + l7 * 8);
    }

    for (int kt = 0; kt < SS / 64; ++kt) {
        __syncthreads();
        *(short8*)&Ks[w * 8 + l8][l7 * 8]      = kreg[0];
        *(short8*)&Ks[32 + w * 8 + l8][l7 * 8] = kreg[1];
        *(short8*)&Vs[w * 8 + l8][l7 * 8]      = vreg[0];
        *(short8*)&Vs[32 + w * 8 + l8][l7 * 8] = vreg[1];
        if (kt + 1 < SS / 64) {
            const short* kb = qkvb + (size_t)(b * SS + (kt + 1) * 64) * 256 + 64;
            kreg[0] = *(const short8*)(kb + (size_t)(w * 8 + l8) * 256 + l7 * 8);
            kreg[1] = *(const short8*)(kb + (size_t)(32 + w * 8 + l8) * 256 + l7 * 8);
            const short* vb = Vtg + (size_t)b * 64 * SS + (kt + 1) * 64;
            vreg[0] = *(const short8*)(vb + (size_t)(w * 8 + l8) * SS + l7 * 8);
            vreg[1] = *(const short8*)(vb + (size_t)(32 + w * 8 + l8) * SS + l7 * 8);
        }
        __syncthreads();

        f32x4 st[4];
#pragma unroll
        for (int mt = 0; mt < 4; ++mt) st[mt] = {0.f, 0.f, 0.f, 0.f};
#pragma unroll
        for (int kc = 0; kc < 2; ++kc)
#pragma unroll
            for (int mt = 0; mt < 4; ++mt) {
                short8 kf = *(const short8*)&Ks[mt * 16 + l15][kc * 32 + lq * 8];
                st[mt] = __builtin_amdgcn_mfma_f32_16x16x32_bf16(kf, qf[kc], st[mt], 0, 0, 0);
            }
        float mx = m_i;
#pragma unroll
        for (int mt = 0; mt < 4; ++mt)
#pragma unroll
            for (int r = 0; r < 4; ++r) {
                st[mt][r] *= sc;
                mx = fmaxf(mx, st[mt][r]);
            }
        mx = fmaxf(mx, __shfl_xor(mx, 16));
        mx = fmaxf(mx, __shfl_xor(mx, 32));
        float alpha = exp2f(m_i - mx);
        float rs = 0.f;
#pragma unroll
        for (int mt = 0; mt < 4; ++mt) {
            s16x4 pk;
#pragma unroll
            for (int r = 0; r < 4; ++r) {
                float p = exp2f(st[mt][r] - mx);
                rs += p;
                pk[r] = f2b(p);
            }
            *(s16x4*)&Ps[w][l15][mt * 16 + lq * 4] = pk;
        }
        rs += __shfl_xor(rs, 16);
        rs += __shfl_xor(rs, 32);
        l_i = l_i * alpha + rs;
        m_i = mx;
#pragma unroll
        for (int mt = 0; mt < 4; ++mt)
#pragma unroll
            for (int r = 0; r < 4; ++r) acc[mt][r] *= alpha;

#pragma unroll
        for (int kc = 0; kc < 2; ++kc) {
            s16x4 p0 = *(const s16x4*)&Ps[w][l15][kc * 32 + lq * 8];
            s16x4 p1 = *(const s16x4*)&Ps[w][l15][kc * 32 + lq * 8 + 4];
            short8 pf = __builtin_shufflevector(p0, p1, 0, 1, 2, 3, 4, 5, 6, 7);
#pragma unroll
            for (int mt = 0; mt < 4; ++mt) {
                short8 vf = *(const short8*)&Vs[mt * 16 + l15][kc * 32 + lq * 8];
                acc[mt] = __builtin_amdgcn_mfma_f32_16x16x32_bf16(vf, pf, acc[mt], 0, 0, 0);
            }
        }
    }
    float inv = 1.0f / l_i;
    short* out = head + (size_t)(b * SS + q0 + w * 16 + l15) * 64;
#pragma unroll
    for (int mt = 0; mt < 4; ++mt) {
        s16x4 o;
#pragma unroll
        for (int r = 0; r < 4; ++r) o[r] = f2b(acc[mt][r] * inv);
        *(s16x4*)&out[mt * 16 + lq * 4] = o;
    }
}

// ---------------------------------------------------------------------------
// Final LN2 normalize: d_out fp32 = (b2f(T1) - mu)*rstd
// ---------------------------------------------------------------------------
__global__ __launch_bounds__(256) void lnfinal_kernel(const short* __restrict__ y,
                                                      float* __restrict__ out,
                                                      const double* __restrict__ red,
                                                      int n) {
    double mean = red[0] / n;
    double var  = red[1] / n - mean * mean;
    float mu   = (float)mean;
    float rstd = (float)(1.0 / sqrt(var + LN_EPS));
    for (int i = blockIdx.x * blockDim.x + threadIdx.x; i < n;
         i += gridDim.x * blockDim.x)
        out[i] = (b2f(y[i]) - mu) * rstd;
}

// ---------------------------------------------------------------------------
extern "C" void kernel_launch(void* const* d_in, const int* in_sizes, int n_in,
                              void* d_out, int out_size, void* d_ws, size_t ws_size,
                              hipStream_t stream) {
    const int*   ids = (const int*)d_in[0];
    const float* emb = (const float*)d_in[1];
    const float* Wq  = (const float*)d_in[2];
    const float* bq  = (const float*)d_in[3];
    const float* Wk  = (const float*)d_in[4];
    const float* bk  = (const float*)d_in[5];
    const float* Wv  = (const float*)d_in[6];
    const float* bv  = (const float*)d_in[7];
    const float* Wo  = (const float*)d_in[8];
    const float* bo  = (const float*)d_in[9];
    const float* W1  = (const float*)d_in[10];
    const float* b1  = (const float*)d_in[11];
    const float* W2  = (const float*)d_in[12];
    const float* b2  = (const float*)d_in[13];

    float* xout = (float*)d_out;                     // final output only
    char* w = (char*)d_ws;

    // Buffers (bf16 unless noted):
    //   hch  [16384][2048] (full) or [8192][2048] (chunked) -- FF hidden
    //   qkvb [16384][256], Vtg [8][64][2048], head [16384][64]  (alias in hch)
    //   T1   trunk y (rep input / FF2 output), T2 trunk z (outproj output)
    const bool big = ws_size >= (size_t)105195712 + 256;

    short *qkvb, *Vtg, *head, *T1, *T2, *hch, *WqkvT, *WoST, *W1T, *W2T;
    float *bqkv, *csq, *csw1; double* red;

    if (big) {
        hch   = (short*)(w + 0);                     // 64 MB
        qkvb  = (short*)(w + 0);                     //  8 MB (alias)
        Vtg   = (short*)(w + 8388608);               //  2 MB (alias)
        head  = (short*)(w + 10485760);              //  2 MB (alias)
        T1    = (short*)(w + 67108864);              // 16 MB
        T2    = (short*)(w + 83886080);              // 16 MB
        WqkvT = (short*)(w + 100663296);
        bqkv  = (float*)(w + 100925440);
        csq   = (float*)(w + 100926464);
        WoST  = (short*)(w + 100927488);
        W1T   = (short*)(w + 100993024);
        csw1  = (float*)(w + 103090176);
        W2T   = (short*)(w + 103098368);
        red   = (double*)(w + 105195520);
    } else {
        hch   = (short*)(w + 0);                     // 32 MB (M=8192 chunks)
        qkvb  = (short*)(w + 0);
        Vtg   = (short*)(w + 8388608);
        head  = (short*)(w + 10485760);
        T1    = (short*)(w + 33554432);
        T2    = (short*)(w + 50331648);
        WqkvT = (short*)(w + 67108864);
        bqkv  = (float*)(w + 67371008);
        csq   = (float*)(w + 67372032);
        WoST  = (short*)(w + 67373056);
        W1T   = (short*)(w + 67438592);
        csw1  = (float*)(w + 69535744);
        W2T   = (short*)(w + 69543936);
        red   = (double*)(w + 71641088);
    }

    // ---- setup (once per launch) ----
    packqkvT_kernel<<<(256 * 512 + 255) / 256, 256, 0, stream>>>(Wq, Wk, Wv, bq, bk, bv, WqkvT, bqkv);
    wosumT_kernel<<<(512 * 64 + 255) / 256, 256, 0, stream>>>(Wo, WoST);
    transpose_b16<<<dim3(2048 / 32, 512 / 32), 256, 0, stream>>>(W1, W1T, 512, 2048);
    transpose_b16<<<dim3(512 / 32, 2048 / 32), 256, 0, stream>>>(W2, W2T, 2048, 512);
    colsum_kernel<<<9, 256, 0, stream>>>(WqkvT, W1T, csq, csw1);
    embed_kernel<<<NTOT / 256, 256, 0, stream>>>(ids, emb, T1, red);

    for (int rep = 0; rep < 6; ++rep) {
        const double* sprev = rep ? red + 4 * (rep - 1) + 2 : nullptr;  // LN2 stats of prev rep
        double* red1 = red + 4 * rep;        // LN1 stats (over z = outproj out)
        double* red2 = red + 4 * rep + 2;    // LN2 stats (over y' = FF2 out)

        // QKV: LN2-folded  qkvb = LN(T1) @ Wqkv + bqkv   [16384][256]
        gemm_mfma<false, false, false, true, 64, 128, 64><<<dim3(256, 2), 256, 0, stream>>>(
            T1, WqkvT, bqkv, csq, nullptr, qkvb, sprev, nullptr, ROWS, 256, DM);
        // V transpose
        vtrans_kernel<<<dim3(SS / 32, 2, BB), 256, 0, stream>>>(qkvb, Vtg);
        // flash attention -> head
        attn_mfma<<<dim3(SS / 64, BB), 256, 0, stream>>>(qkvb, Vtg, head);
        // out-proj: T2 = head @ WoS + bo + LN(T1); stats -> red1
        gemm_mfma<false, true, true, false, 64, 128, 64><<<dim3(256, 4), 256, 0, stream>>>(
            head, WoST, bo, nullptr, T1, T2, sprev, red1, ROWS, DM, DK);
        // FF (LN1 folded into FF1; resid LN1(T2) in FF2; stats -> red2)
        if (big) {
            gemm_mfma<true, false, false, true, 128, 128, 64><<<dim3(128, 16), 256, 0, stream>>>(
                T2, W1T, b1, csw1, nullptr, hch, red1, nullptr, ROWS, DFF, DM);
            gemm_mfma<false, true, true, false, 64, 256, 64><<<dim3(256, 2), 256, 0, stream>>>(
                hch, W2T, b2, nullptr, T2, T1, red1, red2, ROWS, DM, DFF);
        } else {
            for (int c = 0; c < 2; ++c) {
                const size_t off = (size_t)c * 8192 * DM;
                gemm_mfma<true, false, false, true, 128, 128, 64><<<dim3(64, 16), 256, 0, stream>>>(
                    T2 + off, W1T, b1, csw1, nullptr, hch, red1, nullptr, 8192, DFF, DM);
                gemm_mfma<false, true, true, false, 64, 256, 64><<<dim3(128, 2), 256, 0, stream>>>(
                    hch, W2T, b2, nullptr, T2 + off, T1 + off, red1, red2, 8192, DM, DFF);
            }
        }
    }
    // final LN2 normalize -> fp32 output
    lnfinal_kernel<<<4096, 256, 0, stream>>>(T1, xout, red + 4 * 5 + 2, NTOT);
}